// Round 2
// baseline (6452.671 us; speedup 1.0000x reference)
//
#include <hip/hip_runtime.h>

#define NN 50000   // nodes
#define NE 800000  // edges
#define DD 128     // node dim
#define HH 128     // hidden dim
#define RR 64      // num rbf
#define LL 4       // layers
#define GG 64      // graphs

typedef float f4 __attribute__((ext_vector_type(4)));

__device__ __forceinline__ float silu1(float v) { return v / (1.0f + __expf(-v)); }

// ---------------------------------------------------------------------------
// Edge distances: dist[e] = |pos[row] - pos[col]|   (pos is layer-invariant)
// ---------------------------------------------------------------------------
__global__ void dist_kernel(const float* __restrict__ pos,
                            const int* __restrict__ erow, const int* __restrict__ ecol,
                            float* __restrict__ dist)
{
    int e = blockIdx.x * 256 + threadIdx.x;
    if (e >= NE) return;
    int r = erow[e], c = ecol[e];
    float dx = pos[r * 3 + 0] - pos[c * 3 + 0];
    float dy = pos[r * 3 + 1] - pos[c * 3 + 1];
    float dz = pos[r * 3 + 2] - pos[c * 3 + 2];
    dist[e] = sqrtf(dx * dx + dy * dy + dz * dz);
}

// ---------------------------------------------------------------------------
// Zero fill (graph-capture-safe replacement for hipMemsetAsync)
// ---------------------------------------------------------------------------
__global__ void fillz_kernel(float* __restrict__ p, int n4)
{
    int i = blockIdx.x * 256 + threadIdx.x;
    if (i < n4) ((f4*)p)[i] = (f4){0.f, 0.f, 0.f, 0.f};
}

// ---------------------------------------------------------------------------
// Weight folding (per layer):
//   Wpa = W_node @ W_e1[0:128]      (128x128)   multiplies x[col]
//   Wqb = W_node @ W_e1[128:256]    (128x128)   multiplies x[row]
//   Wc  = W_rbf  @ W_e1[256:384]    (64x128)    multiplies rbf
//   b_msg = b_e1 + b_node@(W1a+W1b) + b_rbf@W1c
// ---------------------------------------------------------------------------
__global__ void fold_kernel(const float* __restrict__ Wnode, const float* __restrict__ Wrbf,
                            const float* __restrict__ We1,
                            const float* __restrict__ bnode, const float* __restrict__ brbf,
                            const float* __restrict__ be1,
                            float* __restrict__ Wpa, float* __restrict__ Wqb,
                            float* __restrict__ Wc, float* __restrict__ bmsg)
{
    int l = blockIdx.x >> 2;
    int type = blockIdx.x & 3;
    const float* We1l = We1 + (size_t)l * 384 * 128;
    if (type == 3) {
        int j = threadIdx.x;
        if (j < 128) {
            float s = be1[l * 128 + j];
            for (int k = 0; k < 128; ++k) {
                float w = We1l[k * 128 + j] + We1l[(128 + k) * 128 + j];
                s += bnode[l * 128 + k] * w + brbf[l * 128 + k] * We1l[(256 + k) * 128 + j];
            }
            bmsg[l * 128 + j] = s;
        }
        return;
    }
    const float* A;
    const float* B;
    float* C;
    int M;
    if (type == 0) { A = Wnode + (size_t)l * 128 * 128; B = We1l;            C = Wpa + (size_t)l * 128 * 128; M = 128; }
    else if (type == 1) { A = Wnode + (size_t)l * 128 * 128; B = We1l + 128 * 128; C = Wqb + (size_t)l * 128 * 128; M = 128; }
    else { A = Wrbf + (size_t)l * 64 * 128; B = We1l + 256 * 128; C = Wc + (size_t)l * 64 * 128; M = 64; }
    for (int o = threadIdx.x; o < M * 128; o += 256) {
        int r = o >> 7, c = o & 127;
        float s = 0.0f;
        for (int k = 0; k < 128; ++k) s += A[r * 128 + k] * B[k * 128 + c];
        C[o] = s;
    }
}

// ---------------------------------------------------------------------------
// Dual node GEMM: P = X @ Wpa, Q = X @ Wqb   (X: [N][128], W: [128][128])
// Also zeroes agg rows (runs strictly before edge_kernel each layer).
// block = 256 threads handles 64 rows x 128 cols; thread = 8 rows x 4 cols
// ---------------------------------------------------------------------------
__global__ __launch_bounds__(256, 2)
void nodepq_kernel(const float* __restrict__ X,
                   const float* __restrict__ Wpa, const float* __restrict__ Wqb,
                   float* __restrict__ P, float* __restrict__ Q,
                   float* __restrict__ agg)
{
    __shared__ float s_a[64][128];  // 32 KB
    __shared__ f4 s_wp[16][32];     // 8 KB
    __shared__ f4 s_wq[16][32];     // 8 KB

    const int tid = threadIdx.x;
    const int ci = tid & 31;
    const int ei = tid >> 5;
    const int r0 = blockIdx.x * 64;

    // stage X tile (guard rows) + zero agg rows
    for (int i = tid; i < 64 * 32; i += 256) {
        int rr = i >> 5, cc = i & 31;
        int r = r0 + rr;
        f4 v = {0.f, 0.f, 0.f, 0.f};
        if (r < NN) {
            v = ((const f4*)X)[(size_t)r * 32 + cc];
            ((f4*)agg)[(size_t)r * 32 + cc] = (f4){0.f, 0.f, 0.f, 0.f};
        }
        ((f4*)&s_a[rr][0])[cc] = v;
    }

    f4 accp[8], accq[8];
#pragma unroll
    for (int j = 0; j < 8; ++j) { accp[j] = (f4){0.f, 0.f, 0.f, 0.f}; accq[j] = accp[j]; }

    for (int kt = 0; kt < 128; kt += 16) {
        for (int i = tid; i < 512; i += 256) {
            ((f4*)s_wp)[i] = ((const f4*)(Wpa + (size_t)kt * 128))[i];
            ((f4*)s_wq)[i] = ((const f4*)(Wqb + (size_t)kt * 128))[i];
        }
        __syncthreads();
#pragma unroll
        for (int k = 0; k < 16; ++k) {
            f4 wp = s_wp[k][ci];
            f4 wq = s_wq[k][ci];
#pragma unroll
            for (int j = 0; j < 8; ++j) {
                float a = s_a[ei * 8 + j][kt + k];
                accp[j] += a * wp;
                accq[j] += a * wq;
            }
        }
        __syncthreads();
    }
#pragma unroll
    for (int j = 0; j < 8; ++j) {
        int r = r0 + ei * 8 + j;
        if (r < NN) {
            ((f4*)P)[(size_t)r * 32 + ci] = accp[j];
            ((f4*)Q)[(size_t)r * 32 + ci] = accq[j];
        }
    }
}

// ---------------------------------------------------------------------------
// Fused edge kernel (the hotspot):
//   rbf from dist (in LDS); c = rbf @ Wc (K=64);
//   t = silu(P[col] + Q[row] + c + b_msg);
//   m = t @ W_e2 + b_e2; atomicAdd(agg[col], m)
// block = 256 threads handles 64 edges; thread = 8 edges x 4 cols
// ---------------------------------------------------------------------------
__global__ __launch_bounds__(256, 2)
void edge_kernel(const float* __restrict__ P, const float* __restrict__ Q,
                 const float* __restrict__ dist,
                 const int* __restrict__ erow, const int* __restrict__ ecol,
                 const float* __restrict__ Wc, const float* __restrict__ bmsg,
                 const float* __restrict__ We2, const float* __restrict__ be2,
                 float* __restrict__ agg)
{
    __shared__ float s_t[64][128];  // 32 KB; cols 0..63 hold rbf during phase 1
    __shared__ f4 s_w[32][32];      // 16 KB
    __shared__ int s_row[64], s_col[64];
    __shared__ float s_d[64];

    const int tid = threadIdx.x;
    const int ci = tid & 31;
    const int ei = tid >> 5;
    const int e0 = blockIdx.x * 64;

    if (tid < 64) {
        s_row[tid] = erow[e0 + tid];
        s_col[tid] = ecol[e0 + tid];
        s_d[tid] = dist[e0 + tid];
    }
    __syncthreads();

    // compute rbf for 64 edges x 64 centers into s_t[:, 0:64]
    const float step = 6.0f / 63.0f;
    for (int i = tid; i < 64 * 64; i += 256) {
        int e = i >> 6, r = i & 63;
        float t = s_d[e] - (float)r * step;
        s_t[e][r] = __expf(-10.0f * t * t);
    }

    f4 acc[8];
#pragma unroll
    for (int j = 0; j < 8; ++j) acc[j] = (f4){0.f, 0.f, 0.f, 0.f};

    // phase 1: c = rbf @ Wc  (K = 64)
    for (int kt = 0; kt < 64; kt += 32) {
        for (int i = tid; i < 1024; i += 256)
            ((f4*)s_w)[i] = ((const f4*)(Wc + (size_t)kt * 128))[i];
        __syncthreads();  // also makes s_t rbf visible on first iteration
#pragma unroll
        for (int k = 0; k < 32; ++k) {
            f4 w = s_w[k][ci];
#pragma unroll
            for (int j = 0; j < 8; ++j)
                acc[j] += s_t[ei * 8 + j][kt + k] * w;
        }
        __syncthreads();
    }

    // phase 2: gather P[col], Q[row], bias, silu -> t
    f4 bm = ((const f4*)bmsg)[ci];
#pragma unroll
    for (int j = 0; j < 8; ++j) {
        int e = ei * 8 + j;
        int cN = s_col[e], rN = s_row[e];
        f4 p = ((const f4*)P)[(size_t)cN * 32 + ci];
        f4 q = ((const f4*)Q)[(size_t)rN * 32 + ci];
        f4 v = acc[j] + p + q + bm;
        f4 t;
#pragma unroll
        for (int q2 = 0; q2 < 4; ++q2) t[q2] = silu1(v[q2]);
        acc[j] = t;
    }
    // all phase-1 reads of s_t finished at the trailing sync above -> safe to overwrite
#pragma unroll
    for (int j = 0; j < 8; ++j)
        ((f4*)&s_t[ei * 8 + j][0])[ci] = acc[j];

    // phase 3: m = t @ W_e2  (K = 128)
    f4 acc2[8];
#pragma unroll
    for (int j = 0; j < 8; ++j) acc2[j] = (f4){0.f, 0.f, 0.f, 0.f};
    for (int kt = 0; kt < 128; kt += 32) {
        for (int i = tid; i < 1024; i += 256)
            ((f4*)s_w)[i] = ((const f4*)(We2 + (size_t)kt * 128))[i];
        __syncthreads();  // covers s_t visibility for kt==0 as well
#pragma unroll
        for (int k = 0; k < 32; ++k) {
            f4 w = s_w[k][ci];
#pragma unroll
            for (int j = 0; j < 8; ++j)
                acc2[j] += s_t[ei * 8 + j][kt + k] * w;
        }
        __syncthreads();
    }

    // phase 4: bias + scatter-add
    f4 b2 = ((const f4*)be2)[ci];
#pragma unroll
    for (int j = 0; j < 8; ++j) {
        int e = ei * 8 + j;
        int cN = s_col[e];
        f4 m = acc2[j] + b2;
        float* dst = agg + (size_t)cN * 128 + ci * 4;
        atomicAdd(dst + 0, m[0]);
        atomicAdd(dst + 1, m[1]);
        atomicAdd(dst + 2, m[2]);
        atomicAdd(dst + 3, m[3]);
    }
}

// ---------------------------------------------------------------------------
// Node update: X_out = silu(agg @ W_u1 + b_u1) @ W_u2 + b_u2
// ---------------------------------------------------------------------------
__global__ __launch_bounds__(256, 2)
void nodeupd_kernel(const float* __restrict__ AGG,
                    const float* __restrict__ Wu1, const float* __restrict__ bu1,
                    const float* __restrict__ Wu2, const float* __restrict__ bu2,
                    float* __restrict__ Xout)
{
    __shared__ float s_a[64][128];  // 32 KB: agg tile, then t tile
    __shared__ f4 s_w[32][32];      // 16 KB

    const int tid = threadIdx.x;
    const int ci = tid & 31;
    const int ei = tid >> 5;
    const int r0 = blockIdx.x * 64;

    for (int i = tid; i < 64 * 32; i += 256) {
        int rr = i >> 5, cc = i & 31;
        int r = r0 + rr;
        f4 v = {0.f, 0.f, 0.f, 0.f};
        if (r < NN) v = ((const f4*)AGG)[(size_t)r * 32 + cc];
        ((f4*)&s_a[rr][0])[cc] = v;
    }

    f4 acc[8];
#pragma unroll
    for (int j = 0; j < 8; ++j) acc[j] = (f4){0.f, 0.f, 0.f, 0.f};

    for (int kt = 0; kt < 128; kt += 32) {
        for (int i = tid; i < 1024; i += 256)
            ((f4*)s_w)[i] = ((const f4*)(Wu1 + (size_t)kt * 128))[i];
        __syncthreads();
#pragma unroll
        for (int k = 0; k < 32; ++k) {
            f4 w = s_w[k][ci];
#pragma unroll
            for (int j = 0; j < 8; ++j)
                acc[j] += s_a[ei * 8 + j][kt + k] * w;
        }
        __syncthreads();
    }

    f4 b1 = ((const f4*)bu1)[ci];
#pragma unroll
    for (int j = 0; j < 8; ++j) {
        f4 v = acc[j] + b1;
#pragma unroll
        for (int q2 = 0; q2 < 4; ++q2) v[q2] = silu1(v[q2]);
        acc[j] = v;
    }
#pragma unroll
    for (int j = 0; j < 8; ++j)
        ((f4*)&s_a[ei * 8 + j][0])[ci] = acc[j];

    f4 acc2[8];
#pragma unroll
    for (int j = 0; j < 8; ++j) acc2[j] = (f4){0.f, 0.f, 0.f, 0.f};
    for (int kt = 0; kt < 128; kt += 32) {
        for (int i = tid; i < 1024; i += 256)
            ((f4*)s_w)[i] = ((const f4*)(Wu2 + (size_t)kt * 128))[i];
        __syncthreads();
#pragma unroll
        for (int k = 0; k < 32; ++k) {
            f4 w = s_w[k][ci];
#pragma unroll
            for (int j = 0; j < 8; ++j)
                acc2[j] += s_a[ei * 8 + j][kt + k] * w;
        }
        __syncthreads();
    }

    f4 b2 = ((const f4*)bu2)[ci];
#pragma unroll
    for (int j = 0; j < 8; ++j) {
        int r = r0 + ei * 8 + j;
        if (r < NN) ((f4*)Xout)[(size_t)r * 32 + ci] = acc2[j] + b2;
    }
}

// ---------------------------------------------------------------------------
// Graph readout
// ---------------------------------------------------------------------------
__global__ void gsum_kernel(const float* __restrict__ X, const int* __restrict__ batch,
                            float* __restrict__ Gm)
{
    int idx = blockIdx.x * 256 + threadIdx.x;  // N*32 threads
    if (idx >= NN * 32) return;
    int node = idx >> 5, ci = idx & 31;
    int b = batch[node];
    f4 v = ((const f4*)X)[(size_t)node * 32 + ci];
    float* dst = Gm + (size_t)b * 128 + ci * 4;
    atomicAdd(dst + 0, v[0]);
    atomicAdd(dst + 1, v[1]);
    atomicAdd(dst + 2, v[2]);
    atomicAdd(dst + 3, v[3]);
}

__global__ void final_kernel(const float* __restrict__ Gm,
                             const float* __restrict__ Wf1, const float* __restrict__ bf1,
                             const float* __restrict__ Wf2, const float* __restrict__ bf2,
                             float* __restrict__ out)
{
    __shared__ float red[128];
    int g = blockIdx.x;
    int j = threadIdx.x;  // 128 threads
    float s = bf1[j];
    for (int k = 0; k < 128; ++k) s += Gm[(size_t)g * 128 + k] * Wf1[k * 128 + j];
    s = silu1(s);
    red[j] = s * Wf2[j];
    __syncthreads();
    for (int off = 64; off > 0; off >>= 1) {
        if (j < off) red[j] += red[j + off];
        __syncthreads();
    }
    if (j == 0) out[g] = red[0] + bf2[0];
}

// ---------------------------------------------------------------------------
extern "C" void kernel_launch(void* const* d_in, const int* in_sizes, int n_in,
                              void* d_out, int out_size, void* d_ws, size_t ws_size,
                              hipStream_t stream)
{
    const float* x     = (const float*)d_in[0];
    const float* pos   = (const float*)d_in[1];
    const int*   eidx  = (const int*)d_in[2];
    const int*   batch = (const int*)d_in[3];
    const float* Wnode = (const float*)d_in[4];
    const float* bnode = (const float*)d_in[5];
    const float* Wrbf  = (const float*)d_in[6];
    const float* brbf  = (const float*)d_in[7];
    const float* We1   = (const float*)d_in[8];
    const float* be1   = (const float*)d_in[9];
    const float* We2   = (const float*)d_in[10];
    const float* be2   = (const float*)d_in[11];
    const float* Wu1   = (const float*)d_in[12];
    const float* bu1   = (const float*)d_in[13];
    const float* Wu2   = (const float*)d_in[14];
    const float* bu2   = (const float*)d_in[15];
    const float* Wf1   = (const float*)d_in[16];
    const float* bf1   = (const float*)d_in[17];
    const float* Wf2   = (const float*)d_in[18];
    const float* bf2   = (const float*)d_in[19];

    const int* erow = eidx;
    const int* ecol = eidx + NE;

    char* wsb = (char*)d_ws;
    size_t off = 0;
    auto take = [&](size_t bytes) -> char* {
        char* p = wsb + off;
        off += (bytes + 255) & ~(size_t)255;
        return p;
    };
    float* distb = (float*)take((size_t)NE * 4);            // 3.2 MB
    float* Pb    = (float*)take((size_t)NN * HH * 4);       // 25.6 MB
    float* Qb    = (float*)take((size_t)NN * HH * 4);       // 25.6 MB
    float* aggb  = (float*)take((size_t)NN * HH * 4);       // 25.6 MB
    float* xa    = (float*)take((size_t)NN * DD * 4);       // 25.6 MB
    float* gm    = (float*)take((size_t)GG * DD * 4);
    float* Wpa   = (float*)take((size_t)LL * DD * HH * 4);
    float* Wqb   = (float*)take((size_t)LL * DD * HH * 4);
    float* Wcc   = (float*)take((size_t)LL * RR * HH * 4);
    float* bmsg  = (float*)take((size_t)LL * HH * 4);

    if (off > ws_size) return;  // workspace too small: fail loudly (absmax), not a fault

    dist_kernel<<<(NE + 255) / 256, 256, 0, stream>>>(pos, erow, ecol, distb);
    fold_kernel<<<LL * 4, 256, 0, stream>>>(Wnode, Wrbf, We1, bnode, brbf, be1,
                                            Wpa, Wqb, Wcc, bmsg);

    const int nblk = (NN + 63) / 64;
    const float* xin = x;
    for (int l = 0; l < LL; ++l) {
        nodepq_kernel<<<nblk, 256, 0, stream>>>(xin,
                                                Wpa + (size_t)l * DD * HH,
                                                Wqb + (size_t)l * DD * HH, Pb, Qb, aggb);
        edge_kernel<<<NE / 64, 256, 0, stream>>>(Pb, Qb, distb, erow, ecol,
                                                 Wcc + (size_t)l * RR * HH,
                                                 bmsg + (size_t)l * HH,
                                                 We2 + (size_t)l * HH * HH,
                                                 be2 + (size_t)l * HH, aggb);
        nodeupd_kernel<<<nblk, 256, 0, stream>>>(aggb,
                                                 Wu1 + (size_t)l * HH * HH,
                                                 bu1 + (size_t)l * HH,
                                                 Wu2 + (size_t)l * HH * DD,
                                                 bu2 + (size_t)l * DD, xa);
        xin = xa;
    }

    fillz_kernel<<<(GG * DD / 4 + 255) / 256, 256, 0, stream>>>(gm, GG * DD / 4);
    gsum_kernel<<<(NN * 32 + 255) / 256, 256, 0, stream>>>(xin, batch, gm);
    final_kernel<<<GG, 128, 0, stream>>>(gm, Wf1, bf1, Wf2, bf2, (float*)d_out);
}

// Round 3
// 1714.679 us; speedup vs baseline: 3.7632x; 3.7632x over previous
//
#include <hip/hip_runtime.h>

#define NN 50000   // nodes
#define NE 800000  // edges
#define DD 128     // node dim
#define HH 128     // hidden dim
#define RR 64      // num rbf
#define LL 4       // layers
#define GG 64      // graphs
#define EB 64      // edges per block (edge kernel)

typedef float f4 __attribute__((ext_vector_type(4)));
typedef __attribute__((ext_vector_type(8))) short bf16x8;  // MFMA A/B frag (4 VGPR)
typedef __attribute__((ext_vector_type(4))) float f32x4;   // MFMA C/D frag

__device__ __forceinline__ float silu1(float v) { return v / (1.0f + __expf(-v)); }

// RNE float -> bf16 bits (branchless; inputs finite)
__device__ __forceinline__ unsigned short f2bf(float f)
{
    union { float f; unsigned u; } x; x.f = f;
    unsigned r = x.u + 0x7fffu + ((x.u >> 16) & 1u);
    return (unsigned short)(r >> 16);
}

// ---------------------------------------------------------------------------
// Zero fill
// ---------------------------------------------------------------------------
__global__ void fillz_kernel(float* __restrict__ p, int n4)
{
    int i = blockIdx.x * 256 + threadIdx.x;
    if (i < n4) ((f4*)p)[i] = (f4){0.f, 0.f, 0.f, 0.f};
}

// ---------------------------------------------------------------------------
// Counting sort of edges by col (destination). One-time per call.
// ---------------------------------------------------------------------------
__global__ void hist_kernel(const int* __restrict__ ecol, int* __restrict__ cnt)
{
    int e = blockIdx.x * 256 + threadIdx.x;
    if (e < NE) atomicAdd(&cnt[ecol[e]], 1);
}

__global__ void scan_kernel(const int* __restrict__ cnt, int* __restrict__ cur)
{
    __shared__ int s[1024];
    int t = threadIdx.x;               // 1024 threads, 1 block
    const int CH = 49;                 // 1024*49 = 50176 >= NN
    int a0 = t * CH, a1 = a0 + CH; if (a1 > NN) a1 = NN; if (a0 > NN) a0 = NN;
    int s0 = 0;
    for (int i = a0; i < a1; ++i) s0 += cnt[i];
    s[t] = s0;
    __syncthreads();
    for (int off = 1; off < 1024; off <<= 1) {
        int v = (t >= off) ? s[t - off] : 0;
        __syncthreads();
        s[t] += v;
        __syncthreads();
    }
    int base = (t == 0) ? 0 : s[t - 1];
    for (int i = a0; i < a1; ++i) { cur[i] = base; base += cnt[i]; }
}

__global__ void scatter_kernel(const float* __restrict__ pos,
                               const int* __restrict__ erow, const int* __restrict__ ecol,
                               int* __restrict__ cur,
                               int* __restrict__ srow, int* __restrict__ scol,
                               float* __restrict__ sdist)
{
    int e = blockIdx.x * 256 + threadIdx.x;
    if (e >= NE) return;
    int r = erow[e], c = ecol[e];
    int p = atomicAdd(&cur[c], 1);
    srow[p] = r;
    scol[p] = c;
    float dx = pos[r * 3 + 0] - pos[c * 3 + 0];
    float dy = pos[r * 3 + 1] - pos[c * 3 + 1];
    float dz = pos[r * 3 + 2] - pos[c * 3 + 2];
    sdist[p] = sqrtf(dx * dx + dy * dy + dz * dz);
}

// ---------------------------------------------------------------------------
// Weight folding (fp32):
//   Wpa = W_node @ W_e1[0:128], Wqb = W_node @ W_e1[128:256],
//   Wc  = W_rbf  @ W_e1[256:384], b_msg = b_e1 + b_node@(W1a+W1b) + b_rbf@W1c
// ---------------------------------------------------------------------------
__global__ void fold_kernel(const float* __restrict__ Wnode, const float* __restrict__ Wrbf,
                            const float* __restrict__ We1,
                            const float* __restrict__ bnode, const float* __restrict__ brbf,
                            const float* __restrict__ be1,
                            float* __restrict__ Wpa, float* __restrict__ Wqb,
                            float* __restrict__ Wc, float* __restrict__ bmsg)
{
    int l = blockIdx.x >> 2;
    int type = blockIdx.x & 3;
    const float* We1l = We1 + (size_t)l * 384 * 128;
    if (type == 3) {
        int j = threadIdx.x;
        if (j < 128) {
            float s = be1[l * 128 + j];
            for (int k = 0; k < 128; ++k) {
                float w = We1l[k * 128 + j] + We1l[(128 + k) * 128 + j];
                s += bnode[l * 128 + k] * w + brbf[l * 128 + k] * We1l[(256 + k) * 128 + j];
            }
            bmsg[l * 128 + j] = s;
        }
        return;
    }
    const float* A;
    const float* B;
    float* C;
    int M;
    if (type == 0) { A = Wnode + (size_t)l * 128 * 128; B = We1l;            C = Wpa + (size_t)l * 128 * 128; M = 128; }
    else if (type == 1) { A = Wnode + (size_t)l * 128 * 128; B = We1l + 128 * 128; C = Wqb + (size_t)l * 128 * 128; M = 128; }
    else { A = Wrbf + (size_t)l * 64 * 128; B = We1l + 256 * 128; C = Wc + (size_t)l * 64 * 128; M = 64; }
    for (int o = threadIdx.x; o < M * 128; o += 256) {
        int r = o >> 7, c = o & 127;
        float s = 0.0f;
        for (int k = 0; k < 128; ++k) s += A[r * 128 + k] * B[k * 128 + c];
        C[o] = s;
    }
}

// ---------------------------------------------------------------------------
// Pack fp32 weight M[K][128] into per-lane MFMA B-fragment order, bf16:
//   pk[kc][cbG][lane][j]  with k = kc*32 + (lane>>4)*8 + j, col = cbG*16 + (lane&15)
// ---------------------------------------------------------------------------
__global__ void pack_kernel(const float* __restrict__ M, unsigned short* __restrict__ pk, int K)
{
    int idx = blockIdx.x * 256 + threadIdx.x;
    if (idx >= K * 128) return;
    int k = idx >> 7, c = idx & 127;
    int kc = k >> 5, hi = (k >> 3) & 3, j = k & 7;
    int cbG = c >> 4, lo = c & 15;
    int lane = hi * 16 + lo;
    pk[(((kc * 8 + cbG) * 64 + lane) * 8) + j] = f2bf(M[idx]);
}

// ---------------------------------------------------------------------------
// Dual node GEMM (fp32, unchanged): P = X @ Wpa, Q = X @ Wqb; zeroes agg.
// ---------------------------------------------------------------------------
__global__ __launch_bounds__(256, 2)
void nodepq_kernel(const float* __restrict__ X,
                   const float* __restrict__ Wpa, const float* __restrict__ Wqb,
                   float* __restrict__ P, float* __restrict__ Q,
                   float* __restrict__ agg)
{
    __shared__ float s_a[64][128];
    __shared__ f4 s_wp[16][32];
    __shared__ f4 s_wq[16][32];

    const int tid = threadIdx.x;
    const int ci = tid & 31;
    const int ei = tid >> 5;
    const int r0 = blockIdx.x * 64;

    for (int i = tid; i < 64 * 32; i += 256) {
        int rr = i >> 5, cc = i & 31;
        int r = r0 + rr;
        f4 v = {0.f, 0.f, 0.f, 0.f};
        if (r < NN) {
            v = ((const f4*)X)[(size_t)r * 32 + cc];
            ((f4*)agg)[(size_t)r * 32 + cc] = (f4){0.f, 0.f, 0.f, 0.f};
        }
        ((f4*)&s_a[rr][0])[cc] = v;
    }

    f4 accp[8], accq[8];
#pragma unroll
    for (int j = 0; j < 8; ++j) { accp[j] = (f4){0.f, 0.f, 0.f, 0.f}; accq[j] = accp[j]; }

    for (int kt = 0; kt < 128; kt += 16) {
        for (int i = tid; i < 512; i += 256) {
            ((f4*)s_wp)[i] = ((const f4*)(Wpa + (size_t)kt * 128))[i];
            ((f4*)s_wq)[i] = ((const f4*)(Wqb + (size_t)kt * 128))[i];
        }
        __syncthreads();
#pragma unroll
        for (int k = 0; k < 16; ++k) {
            f4 wp = s_wp[k][ci];
            f4 wq = s_wq[k][ci];
#pragma unroll
            for (int j = 0; j < 8; ++j) {
                float a = s_a[ei * 8 + j][kt + k];
                accp[j] += a * wp;
                accq[j] += a * wq;
            }
        }
        __syncthreads();
    }
#pragma unroll
    for (int j = 0; j < 8; ++j) {
        int r = r0 + ei * 8 + j;
        if (r < NN) {
            ((f4*)P)[(size_t)r * 32 + ci] = accp[j];
            ((f4*)Q)[(size_t)r * 32 + ci] = accq[j];
        }
    }
}

// ---------------------------------------------------------------------------
// MFMA edge kernel. Block = 256 thr = 4 waves; 64 sorted edges; wave w owns
// output cols [32w, 32w+32).  C/D layout: row=(lane>>4)*4+reg, col=lane&15.
// Phase1: C1 = RBF(sdist) @ Wc (K=64, A-frags computed in-register)
// Phase2: t = silu(C1 + P[col] + Q[row] + bmsg) -> bf16 LDS (XOR-swizzled)
// Phase3: M = T @ We2 (K=128, A from LDS, B pre-packed from global)
// Phase4: per-run (equal scol) shfl-reduce + one atomicAdd per node-col
// ---------------------------------------------------------------------------
__global__ __launch_bounds__(256, 3)
void edge_mfma_kernel(const float* __restrict__ P, const float* __restrict__ Q,
                      const float* __restrict__ sdist,
                      const int* __restrict__ srow, const int* __restrict__ scol,
                      const unsigned short* __restrict__ pk1,  // [2][8][64][8]
                      const unsigned short* __restrict__ pk3,  // [4][8][64][8]
                      const float* __restrict__ bmsg, const float* __restrict__ be2,
                      float* __restrict__ agg)
{
    __shared__ unsigned short s_t[EB * 128];  // 16 KB, swizzled: byte = e*256 + (c*2 ^ ((e&7)<<4))
    __shared__ float s_d[EB];
    __shared__ int s_row[EB], s_col[EB];
    __shared__ int s_rs[EB + 1];
    __shared__ int s_nr;

    const int tid = threadIdx.x;
    const int w = tid >> 6;
    const int lane = tid & 63;
    const int lo = lane & 15, hi = lane >> 4;
    const int e0 = blockIdx.x * EB;
    const int colbase = w * 32;

    if (tid < EB) {
        s_d[tid] = sdist[e0 + tid];
        s_row[tid] = srow[e0 + tid];
        s_col[tid] = scol[e0 + tid];
    }
    __syncthreads();

    // run boundaries from sorted scol (wave 0 only)
    if (w == 0) {
        int c = s_col[lane];
        bool flag = (lane == 0) || (c != s_col[lane - 1]);
        unsigned long long m = __ballot(flag);
        if (flag) {
            int rank = __popcll(m & ((1ull << lane) - 1ull));
            s_rs[rank] = lane;
        }
        if (lane == 0) {
            int nr = __popcll(m);
            s_nr = nr;
            s_rs[nr] = EB;
        }
    }
    // (visibility of s_rs/s_nr guaranteed by the barrier before phase 3)

    // ---- phase 1: C1 = RBF @ Wc  (K = 64)
    f32x4 acc[4][2];
#pragma unroll
    for (int rb = 0; rb < 4; ++rb)
#pragma unroll
        for (int cb = 0; cb < 2; ++cb) acc[rb][cb] = (f32x4){0.f, 0.f, 0.f, 0.f};

    float dv[4];
#pragma unroll
    for (int rb = 0; rb < 4; ++rb) dv[rb] = s_d[rb * 16 + lo];

    const float step = 6.0f / 63.0f;
#pragma unroll
    for (int kc = 0; kc < 2; ++kc) {
        bf16x8 a[4];
#pragma unroll
        for (int rb = 0; rb < 4; ++rb) {
            union { bf16x8 v; unsigned short u[8]; } U;
#pragma unroll
            for (int j = 0; j < 8; ++j) {
                float cc = (float)(kc * 32 + hi * 8 + j) * step;
                float t = dv[rb] - cc;
                U.u[j] = f2bf(__expf(-10.0f * t * t));
            }
            a[rb] = U.v;
        }
#pragma unroll
        for (int cb = 0; cb < 2; ++cb) {
            bf16x8 b = *reinterpret_cast<const bf16x8*>(
                pk1 + ((size_t)((kc * 8 + w * 2 + cb) * 64 + lane)) * 8);
#pragma unroll
            for (int rb = 0; rb < 4; ++rb)
                acc[rb][cb] = __builtin_amdgcn_mfma_f32_16x16x32_bf16(a[rb], b, acc[rb][cb], 0, 0, 0);
        }
    }

    // ---- phase 2: t = silu(C1 + P[col] + Q[row] + bmsg) -> bf16 LDS
    float bm[2];
#pragma unroll
    for (int cb = 0; cb < 2; ++cb) bm[cb] = bmsg[colbase + cb * 16 + lo];

#pragma unroll
    for (int rb = 0; rb < 4; ++rb) {
#pragma unroll
        for (int r = 0; r < 4; ++r) {
            int e = rb * 16 + hi * 4 + r;
            int nc = s_col[e], nrw = s_row[e];
#pragma unroll
            for (int cb = 0; cb < 2; ++cb) {
                int c = colbase + cb * 16 + lo;
                float v = acc[rb][cb][r] + P[(size_t)nc * 128 + c] + Q[(size_t)nrw * 128 + c] + bm[cb];
                float t = silu1(v);
                int byte = e * 256 + ((c * 2) ^ ((e & 7) << 4));
                *(unsigned short*)((char*)s_t + byte) = f2bf(t);
            }
        }
    }
    __syncthreads();

    // ---- phase 3: M = T @ We2  (K = 128)
    f32x4 acc2[4][2];
#pragma unroll
    for (int rb = 0; rb < 4; ++rb)
#pragma unroll
        for (int cb = 0; cb < 2; ++cb) acc2[rb][cb] = (f32x4){0.f, 0.f, 0.f, 0.f};

#pragma unroll
    for (int kc = 0; kc < 4; ++kc) {
        bf16x8 a[4];
#pragma unroll
        for (int rb = 0; rb < 4; ++rb) {
            int row = rb * 16 + lo;
            int byte = row * 256 + ((kc * 64 + hi * 16) ^ ((row & 7) << 4));
            a[rb] = *reinterpret_cast<const bf16x8*>((const char*)s_t + byte);
        }
#pragma unroll
        for (int cb = 0; cb < 2; ++cb) {
            bf16x8 b = *reinterpret_cast<const bf16x8*>(
                pk3 + ((size_t)((kc * 8 + w * 2 + cb) * 64 + lane)) * 8);
#pragma unroll
            for (int rb = 0; rb < 4; ++rb)
                acc2[rb][cb] = __builtin_amdgcn_mfma_f32_16x16x32_bf16(a[rb], b, acc2[rb][cb], 0, 0, 0);
        }
    }

    // ---- phase 4: per-run reduce + atomicAdd (+ run_len * be2)
    float be2c[2];
#pragma unroll
    for (int cb = 0; cb < 2; ++cb) be2c[cb] = be2[colbase + cb * 16 + lo];

    int nruns = s_nr;
    for (int ri = 0; ri < nruns; ++ri) {
        int a0 = s_rs[ri], b0 = s_rs[ri + 1];
        int node = s_col[a0];
        float s0 = 0.f, s1 = 0.f;
#pragma unroll
        for (int rb = 0; rb < 4; ++rb)
#pragma unroll
            for (int r = 0; r < 4; ++r) {
                int e = rb * 16 + hi * 4 + r;
                bool in = (e >= a0) && (e < b0);
                s0 += in ? acc2[rb][0][r] : 0.f;
                s1 += in ? acc2[rb][1][r] : 0.f;
            }
        s0 += __shfl_xor(s0, 16, 64); s0 += __shfl_xor(s0, 32, 64);
        s1 += __shfl_xor(s1, 16, 64); s1 += __shfl_xor(s1, 32, 64);
        if (hi == 0) {
            float len = (float)(b0 - a0);
            atomicAdd(agg + (size_t)node * 128 + colbase + lo, s0 + len * be2c[0]);
            atomicAdd(agg + (size_t)node * 128 + colbase + 16 + lo, s1 + len * be2c[1]);
        }
    }
}

// ---------------------------------------------------------------------------
// Node update (fp32, unchanged): X_out = silu(agg @ W_u1 + b_u1) @ W_u2 + b_u2
// ---------------------------------------------------------------------------
__global__ __launch_bounds__(256, 2)
void nodeupd_kernel(const float* __restrict__ AGG,
                    const float* __restrict__ Wu1, const float* __restrict__ bu1,
                    const float* __restrict__ Wu2, const float* __restrict__ bu2,
                    float* __restrict__ Xout)
{
    __shared__ float s_a[64][128];
    __shared__ f4 s_w[32][32];

    const int tid = threadIdx.x;
    const int ci = tid & 31;
    const int ei = tid >> 5;
    const int r0 = blockIdx.x * 64;

    for (int i = tid; i < 64 * 32; i += 256) {
        int rr = i >> 5, cc = i & 31;
        int r = r0 + rr;
        f4 v = {0.f, 0.f, 0.f, 0.f};
        if (r < NN) v = ((const f4*)AGG)[(size_t)r * 32 + cc];
        ((f4*)&s_a[rr][0])[cc] = v;
    }

    f4 acc[8];
#pragma unroll
    for (int j = 0; j < 8; ++j) acc[j] = (f4){0.f, 0.f, 0.f, 0.f};

    for (int kt = 0; kt < 128; kt += 32) {
        for (int i = tid; i < 1024; i += 256)
            ((f4*)s_w)[i] = ((const f4*)(Wu1 + (size_t)kt * 128))[i];
        __syncthreads();
#pragma unroll
        for (int k = 0; k < 32; ++k) {
            f4 w = s_w[k][ci];
#pragma unroll
            for (int j = 0; j < 8; ++j)
                acc[j] += s_a[ei * 8 + j][kt + k] * w;
        }
        __syncthreads();
    }

    f4 b1 = ((const f4*)bu1)[ci];
#pragma unroll
    for (int j = 0; j < 8; ++j) {
        f4 v = acc[j] + b1;
#pragma unroll
        for (int q2 = 0; q2 < 4; ++q2) v[q2] = silu1(v[q2]);
        acc[j] = v;
    }
#pragma unroll
    for (int j = 0; j < 8; ++j)
        ((f4*)&s_a[ei * 8 + j][0])[ci] = acc[j];

    f4 acc2[8];
#pragma unroll
    for (int j = 0; j < 8; ++j) acc2[j] = (f4){0.f, 0.f, 0.f, 0.f};
    for (int kt = 0; kt < 128; kt += 32) {
        for (int i = tid; i < 1024; i += 256)
            ((f4*)s_w)[i] = ((const f4*)(Wu2 + (size_t)kt * 128))[i];
        __syncthreads();
#pragma unroll
        for (int k = 0; k < 32; ++k) {
            f4 w = s_w[k][ci];
#pragma unroll
            for (int j = 0; j < 8; ++j)
                acc2[j] += s_a[ei * 8 + j][kt + k] * w;
        }
        __syncthreads();
    }

    f4 b2 = ((const f4*)bu2)[ci];
#pragma unroll
    for (int j = 0; j < 8; ++j) {
        int r = r0 + ei * 8 + j;
        if (r < NN) ((f4*)Xout)[(size_t)r * 32 + ci] = acc2[j] + b2;
    }
}

// ---------------------------------------------------------------------------
// Graph readout
// ---------------------------------------------------------------------------
__global__ void gsum_kernel(const float* __restrict__ X, const int* __restrict__ batch,
                            float* __restrict__ Gm)
{
    int idx = blockIdx.x * 256 + threadIdx.x;
    if (idx >= NN * 32) return;
    int node = idx >> 5, ci = idx & 31;
    int b = batch[node];
    f4 v = ((const f4*)X)[(size_t)node * 32 + ci];
    float* dst = Gm + (size_t)b * 128 + ci * 4;
    atomicAdd(dst + 0, v[0]);
    atomicAdd(dst + 1, v[1]);
    atomicAdd(dst + 2, v[2]);
    atomicAdd(dst + 3, v[3]);
}

__global__ void final_kernel(const float* __restrict__ Gm,
                             const float* __restrict__ Wf1, const float* __restrict__ bf1,
                             const float* __restrict__ Wf2, const float* __restrict__ bf2,
                             float* __restrict__ out)
{
    __shared__ float red[128];
    int g = blockIdx.x;
    int j = threadIdx.x;
    float s = bf1[j];
    for (int k = 0; k < 128; ++k) s += Gm[(size_t)g * 128 + k] * Wf1[k * 128 + j];
    s = silu1(s);
    red[j] = s * Wf2[j];
    __syncthreads();
    for (int off = 64; off > 0; off >>= 1) {
        if (j < off) red[j] += red[j + off];
        __syncthreads();
    }
    if (j == 0) out[g] = red[0] + bf2[0];
}

// ---------------------------------------------------------------------------
extern "C" void kernel_launch(void* const* d_in, const int* in_sizes, int n_in,
                              void* d_out, int out_size, void* d_ws, size_t ws_size,
                              hipStream_t stream)
{
    const float* x     = (const float*)d_in[0];
    const float* pos   = (const float*)d_in[1];
    const int*   eidx  = (const int*)d_in[2];
    const int*   batch = (const int*)d_in[3];
    const float* Wnode = (const float*)d_in[4];
    const float* bnode = (const float*)d_in[5];
    const float* Wrbf  = (const float*)d_in[6];
    const float* brbf  = (const float*)d_in[7];
    const float* We1   = (const float*)d_in[8];
    const float* be1   = (const float*)d_in[9];
    const float* We2   = (const float*)d_in[10];
    const float* be2   = (const float*)d_in[11];
    const float* Wu1   = (const float*)d_in[12];
    const float* bu1   = (const float*)d_in[13];
    const float* Wu2   = (const float*)d_in[14];
    const float* bu2   = (const float*)d_in[15];
    const float* Wf1   = (const float*)d_in[16];
    const float* bf1   = (const float*)d_in[17];
    const float* Wf2   = (const float*)d_in[18];
    const float* bf2   = (const float*)d_in[19];

    const int* erow = eidx;
    const int* ecol = eidx + NE;

    char* wsb = (char*)d_ws;
    size_t off = 0;
    auto take = [&](size_t bytes) -> char* {
        char* p = wsb + off;
        off += (bytes + 255) & ~(size_t)255;
        return p;
    };
    float* Pb    = (float*)take((size_t)NN * HH * 4);
    float* Qb    = (float*)take((size_t)NN * HH * 4);
    float* aggb  = (float*)take((size_t)NN * HH * 4);
    float* xa    = (float*)take((size_t)NN * DD * 4);
    float* gm    = (float*)take((size_t)GG * DD * 4);
    float* Wpa   = (float*)take((size_t)LL * DD * HH * 4);
    float* Wqb   = (float*)take((size_t)LL * DD * HH * 4);
    float* Wcc   = (float*)take((size_t)LL * RR * HH * 4);
    float* bmsg  = (float*)take((size_t)LL * HH * 4);
    int*   cnt   = (int*)take((size_t)NN * 4);
    int*   cur   = (int*)take((size_t)NN * 4);
    int*   srow  = (int*)take((size_t)NE * 4);
    int*   scol  = (int*)take((size_t)NE * 4);
    float* sdist = (float*)take((size_t)NE * 4);
    unsigned short* pk1 = (unsigned short*)take((size_t)LL * RR * HH * 2);  // [L][2][8][64][8]
    unsigned short* pk3 = (unsigned short*)take((size_t)LL * HH * HH * 2);  // [L][4][8][64][8]

    if (off > ws_size) return;  // fail loudly (absmax), not a fault

    // ---- one-time preprocessing
    fillz_kernel<<<(NN + 1023) / 1024, 256, 0, stream>>>((float*)cnt, NN / 4);
    hist_kernel<<<(NE + 255) / 256, 256, 0, stream>>>(ecol, cnt);
    scan_kernel<<<1, 1024, 0, stream>>>(cnt, cur);
    scatter_kernel<<<(NE + 255) / 256, 256, 0, stream>>>(pos, erow, ecol, cur, srow, scol, sdist);

    fold_kernel<<<LL * 4, 256, 0, stream>>>(Wnode, Wrbf, We1, bnode, brbf, be1,
                                            Wpa, Wqb, Wcc, bmsg);
    for (int l = 0; l < LL; ++l) {
        pack_kernel<<<(RR * HH + 255) / 256, 256, 0, stream>>>(
            Wcc + (size_t)l * RR * HH, pk1 + (size_t)l * RR * HH, RR);
        pack_kernel<<<(HH * HH + 255) / 256, 256, 0, stream>>>(
            We2 + (size_t)l * HH * HH, pk3 + (size_t)l * HH * HH, HH);
    }

    // ---- layers
    const int nblk = (NN + 63) / 64;
    const float* xin = x;
    for (int l = 0; l < LL; ++l) {
        nodepq_kernel<<<nblk, 256, 0, stream>>>(xin,
                                                Wpa + (size_t)l * DD * HH,
                                                Wqb + (size_t)l * DD * HH, Pb, Qb, aggb);
        edge_mfma_kernel<<<NE / EB, 256, 0, stream>>>(Pb, Qb, sdist, srow, scol,
                                                      pk1 + (size_t)l * RR * HH,
                                                      pk3 + (size_t)l * HH * HH,
                                                      bmsg + (size_t)l * HH,
                                                      be2 + (size_t)l * HH, aggb);
        nodeupd_kernel<<<nblk, 256, 0, stream>>>(aggb,
                                                 Wu1 + (size_t)l * HH * HH,
                                                 bu1 + (size_t)l * HH,
                                                 Wu2 + (size_t)l * HH * DD,
                                                 bu2 + (size_t)l * DD, xa);
        xin = xa;
    }

    fillz_kernel<<<(GG * DD / 4 + 255) / 256, 256, 0, stream>>>(gm, GG * DD / 4);
    gsum_kernel<<<(NN * 32 + 255) / 256, 256, 0, stream>>>(xin, batch, gm);
    final_kernel<<<GG, 128, 0, stream>>>(gm, Wf1, bf1, Wf2, bf2, (float*)d_out);
}

// Round 6
// 1206.814 us; speedup vs baseline: 5.3469x; 1.4208x over previous
//
#include <hip/hip_runtime.h>

#define NN 50000   // nodes
#define NE 800000  // edges
#define DD 128     // node dim
#define HH 128     // hidden dim
#define RR 64      // num rbf
#define LL 4       // layers
#define GG 64      // graphs
#define EB 64      // edges per block (edge kernel)

typedef float f4 __attribute__((ext_vector_type(4)));
typedef __attribute__((ext_vector_type(8))) short bf16x8;  // MFMA A/B frag (4 VGPR)
typedef __attribute__((ext_vector_type(4))) float f32x4;   // MFMA C/D frag

__device__ __forceinline__ float silu1(float v) { return v / (1.0f + __expf(-v)); }

// RNE float -> bf16 bits (branchless; inputs finite)
__device__ __forceinline__ unsigned short f2bf(float f)
{
    union { float f; unsigned u; } x; x.f = f;
    unsigned r = x.u + 0x7fffu + ((x.u >> 16) & 1u);
    return (unsigned short)(r >> 16);
}
__device__ __forceinline__ float bf2f(unsigned short h)
{
    union { unsigned u; float f; } x; x.u = ((unsigned)h) << 16; return x.f;
}

// ---------------------------------------------------------------------------
// Zero fill
// ---------------------------------------------------------------------------
__global__ void fillz_kernel(float* __restrict__ p, int n4)
{
    int i = blockIdx.x * 256 + threadIdx.x;
    if (i < n4) ((f4*)p)[i] = (f4){0.f, 0.f, 0.f, 0.f};
}

// ---------------------------------------------------------------------------
// Counting sort of edges by col (destination). One-time per call.
// ---------------------------------------------------------------------------
__global__ void hist_kernel(const int* __restrict__ ecol, int* __restrict__ cnt)
{
    int e = blockIdx.x * 256 + threadIdx.x;
    if (e < NE) atomicAdd(&cnt[ecol[e]], 1);
}

__global__ void scan_kernel(const int* __restrict__ cnt, int* __restrict__ cur)
{
    __shared__ int s[1024];
    int t = threadIdx.x;               // 1024 threads, 1 block
    const int CH = 49;                 // 1024*49 = 50176 >= NN
    int a0 = t * CH, a1 = a0 + CH; if (a1 > NN) a1 = NN; if (a0 > NN) a0 = NN;
    int s0 = 0;
    for (int i = a0; i < a1; ++i) s0 += cnt[i];
    s[t] = s0;
    __syncthreads();
    for (int off = 1; off < 1024; off <<= 1) {
        int v = (t >= off) ? s[t - off] : 0;
        __syncthreads();
        s[t] += v;
        __syncthreads();
    }
    int base = (t == 0) ? 0 : s[t - 1];
    for (int i = a0; i < a1; ++i) { cur[i] = base; base += cnt[i]; }
}

__global__ void scatter_kernel(const float* __restrict__ pos,
                               const int* __restrict__ erow, const int* __restrict__ ecol,
                               int* __restrict__ cur,
                               int* __restrict__ srow, int* __restrict__ scol,
                               float* __restrict__ sdist)
{
    int e = blockIdx.x * 256 + threadIdx.x;
    if (e >= NE) return;
    int r = erow[e], c = ecol[e];
    int p = atomicAdd(&cur[c], 1);
    srow[p] = r;
    scol[p] = c;
    float dx = pos[r * 3 + 0] - pos[c * 3 + 0];
    float dy = pos[r * 3 + 1] - pos[c * 3 + 1];
    float dz = pos[r * 3 + 2] - pos[c * 3 + 2];
    sdist[p] = sqrtf(dx * dx + dy * dy + dz * dz);
}

// ---------------------------------------------------------------------------
// Graph segment boundaries from sorted batch
// ---------------------------------------------------------------------------
__global__ void gstart_kernel(const int* __restrict__ batch, int* __restrict__ gstart)
{
    int i = blockIdx.x * 256 + threadIdx.x;
    if (i >= NN) return;
    int b = batch[i];
    if (i == 0) {
        for (int g = 0; g <= b; ++g) gstart[g] = 0;
    } else {
        int bp = batch[i - 1];
        for (int g = bp + 1; g <= b; ++g) gstart[g] = i;
    }
    if (i == NN - 1) {
        for (int g = b + 1; g <= GG; ++g) gstart[g] = NN;
    }
}

// ---------------------------------------------------------------------------
// Weight folding (fp32)
// ---------------------------------------------------------------------------
__global__ void fold_kernel(const float* __restrict__ Wnode, const float* __restrict__ Wrbf,
                            const float* __restrict__ We1,
                            const float* __restrict__ bnode, const float* __restrict__ brbf,
                            const float* __restrict__ be1,
                            float* __restrict__ Wpa, float* __restrict__ Wqb,
                            float* __restrict__ Wc, float* __restrict__ bmsg)
{
    int l = blockIdx.x >> 2;
    int type = blockIdx.x & 3;
    const float* We1l = We1 + (size_t)l * 384 * 128;
    if (type == 3) {
        int j = threadIdx.x;
        if (j < 128) {
            float s = be1[l * 128 + j];
            for (int k = 0; k < 128; ++k) {
                float w = We1l[k * 128 + j] + We1l[(128 + k) * 128 + j];
                s += bnode[l * 128 + k] * w + brbf[l * 128 + k] * We1l[(256 + k) * 128 + j];
            }
            bmsg[l * 128 + j] = s;
        }
        return;
    }
    const float* A;
    const float* B;
    float* C;
    int M;
    if (type == 0) { A = Wnode + (size_t)l * 128 * 128; B = We1l;            C = Wpa + (size_t)l * 128 * 128; M = 128; }
    else if (type == 1) { A = Wnode + (size_t)l * 128 * 128; B = We1l + 128 * 128; C = Wqb + (size_t)l * 128 * 128; M = 128; }
    else { A = Wrbf + (size_t)l * 64 * 128; B = We1l + 256 * 128; C = Wc + (size_t)l * 64 * 128; M = 64; }
    for (int o = threadIdx.x; o < M * 128; o += 256) {
        int r = o >> 7, c = o & 127;
        float s = 0.0f;
        for (int k = 0; k < 128; ++k) s += A[r * 128 + k] * B[k * 128 + c];
        C[o] = s;
    }
}

// ---------------------------------------------------------------------------
// Pack fp32 weight M[K][128] into per-lane MFMA B-fragment order, bf16
// ---------------------------------------------------------------------------
__global__ void pack_kernel(const float* __restrict__ M, unsigned short* __restrict__ pk, int K)
{
    int idx = blockIdx.x * 256 + threadIdx.x;
    if (idx >= K * 128) return;
    int k = idx >> 7, c = idx & 127;
    int kc = k >> 5, hi = (k >> 3) & 3, j = k & 7;
    int cbG = c >> 4, lo = c & 15;
    int lane = hi * 16 + lo;
    pk[(((kc * 8 + cbG) * 64 + lane) * 8) + j] = f2bf(M[idx]);
}

// Same, but hi/lo split pair (for node-path weights: removes B-quant error)
__global__ void pack2_kernel(const float* __restrict__ M,
                             unsigned short* __restrict__ pkh,
                             unsigned short* __restrict__ pkl, int K)
{
    int idx = blockIdx.x * 256 + threadIdx.x;
    if (idx >= K * 128) return;
    int k = idx >> 7, c = idx & 127;
    int kc = k >> 5, hi = (k >> 3) & 3, j = k & 7;
    int cbG = c >> 4, lo = c & 15;
    int lane = hi * 16 + lo;
    int o = (((kc * 8 + cbG) * 64 + lane) * 8) + j;
    float v = M[idx];
    unsigned short h = f2bf(v);
    pkh[o] = h;
    pkl[o] = f2bf(v - bf2f(h));
}

// ---------------------------------------------------------------------------
// MFMA dual node GEMM, split-precision A AND B (3-term products):
//   P = X @ Wpa, Q = X @ Wqb; also zeroes agg rows.
// Block = 4 waves; 64 rows; wave w owns cols [32w,32w+32).
// ---------------------------------------------------------------------------
__global__ __launch_bounds__(256, 2)
void nodepq_kernel(const float* __restrict__ X,
                   const unsigned short* __restrict__ pkpah,
                   const unsigned short* __restrict__ pkpal,
                   const unsigned short* __restrict__ pkqbh,
                   const unsigned short* __restrict__ pkqbl,
                   float* __restrict__ P, float* __restrict__ Q,
                   float* __restrict__ agg)
{
    __shared__ unsigned short s_h[64 * 128];  // 16 KB, swizzled (hi)
    __shared__ unsigned short s_l[64 * 128];  // 16 KB, swizzled (lo)

    const int tid = threadIdx.x;
    const int w = tid >> 6;
    const int lane = tid & 63;
    const int lo = lane & 15, hi = lane >> 4;
    const int r0 = blockIdx.x * 64;
    const int colbase = w * 32;

    // stage X tile -> hi/lo bf16 swizzled LDS
    for (int i = tid; i < 1024; i += 256) {
        int e = i >> 4, cg = i & 15;  // row e, cols cg*8..cg*8+7
        int r = r0 + e;
        union { unsigned short u16[8]; f4 v; } H, L;
        if (r < NN) {
            f4 v0 = ((const f4*)X)[(size_t)r * 32 + cg * 2];
            f4 v1 = ((const f4*)X)[(size_t)r * 32 + cg * 2 + 1];
#pragma unroll
            for (int q = 0; q < 4; ++q) {
                unsigned short h0 = f2bf(v0[q]);
                unsigned short h1 = f2bf(v1[q]);
                H.u16[q] = h0;     L.u16[q] = f2bf(v0[q] - bf2f(h0));
                H.u16[4 + q] = h1; L.u16[4 + q] = f2bf(v1[q] - bf2f(h1));
            }
        } else {
#pragma unroll
            for (int q = 0; q < 8; ++q) { H.u16[q] = 0; L.u16[q] = 0; }
        }
        int byte = e * 256 + ((cg * 16) ^ ((e & 7) << 4));
        *reinterpret_cast<f4*>((char*)s_h + byte) = H.v;
        *reinterpret_cast<f4*>((char*)s_l + byte) = L.v;
    }
    // zero agg rows
    for (int i = tid; i < 2048; i += 256) {
        int e = i >> 5, cc = i & 31;
        int r = r0 + e;
        if (r < NN) ((f4*)agg)[(size_t)r * 32 + cc] = (f4){0.f, 0.f, 0.f, 0.f};
    }
    __syncthreads();

    f32x4 accp[4][2], accq[4][2];
#pragma unroll
    for (int rb = 0; rb < 4; ++rb)
#pragma unroll
        for (int cb = 0; cb < 2; ++cb) {
            accp[rb][cb] = (f32x4){0.f, 0.f, 0.f, 0.f};
            accq[rb][cb] = (f32x4){0.f, 0.f, 0.f, 0.f};
        }

#pragma unroll
    for (int kc = 0; kc < 4; ++kc) {
        bf16x8 ah[4], al[4];
#pragma unroll
        for (int rb = 0; rb < 4; ++rb) {
            int row = rb * 16 + lo;
            int byte = row * 256 + ((kc * 64 + hi * 16) ^ ((row & 7) << 4));
            ah[rb] = *reinterpret_cast<const bf16x8*>((const char*)s_h + byte);
            al[rb] = *reinterpret_cast<const bf16x8*>((const char*)s_l + byte);
        }
#pragma unroll
        for (int cb = 0; cb < 2; ++cb) {
            size_t boff = ((size_t)((kc * 8 + w * 2 + cb) * 64 + lane)) * 8;
            bf16x8 bph = *reinterpret_cast<const bf16x8*>(pkpah + boff);
            bf16x8 bpl = *reinterpret_cast<const bf16x8*>(pkpal + boff);
            bf16x8 bqh = *reinterpret_cast<const bf16x8*>(pkqbh + boff);
            bf16x8 bql = *reinterpret_cast<const bf16x8*>(pkqbl + boff);
#pragma unroll
            for (int rb = 0; rb < 4; ++rb) {
                accp[rb][cb] = __builtin_amdgcn_mfma_f32_16x16x32_bf16(ah[rb], bph, accp[rb][cb], 0, 0, 0);
                accp[rb][cb] = __builtin_amdgcn_mfma_f32_16x16x32_bf16(al[rb], bph, accp[rb][cb], 0, 0, 0);
                accp[rb][cb] = __builtin_amdgcn_mfma_f32_16x16x32_bf16(ah[rb], bpl, accp[rb][cb], 0, 0, 0);
                accq[rb][cb] = __builtin_amdgcn_mfma_f32_16x16x32_bf16(ah[rb], bqh, accq[rb][cb], 0, 0, 0);
                accq[rb][cb] = __builtin_amdgcn_mfma_f32_16x16x32_bf16(al[rb], bqh, accq[rb][cb], 0, 0, 0);
                accq[rb][cb] = __builtin_amdgcn_mfma_f32_16x16x32_bf16(ah[rb], bql, accq[rb][cb], 0, 0, 0);
            }
        }
    }

    // epilogue: C/D layout row=(lane>>4)*4+reg, col=lane&15
#pragma unroll
    for (int rb = 0; rb < 4; ++rb)
#pragma unroll
        for (int r = 0; r < 4; ++r) {
            int row = r0 + rb * 16 + hi * 4 + r;
            if (row < NN) {
#pragma unroll
                for (int cb = 0; cb < 2; ++cb) {
                    int col = colbase + cb * 16 + lo;
                    P[(size_t)row * 128 + col] = accp[rb][cb][r];
                    Q[(size_t)row * 128 + col] = accq[rb][cb][r];
                }
            }
        }
}

// ---------------------------------------------------------------------------
// MFMA edge kernel (unchanged, round-3 proven). Block = 4 waves; 64 sorted edges.
// ---------------------------------------------------------------------------
__global__ __launch_bounds__(256, 3)
void edge_mfma_kernel(const float* __restrict__ P, const float* __restrict__ Q,
                      const float* __restrict__ sdist,
                      const int* __restrict__ srow, const int* __restrict__ scol,
                      const unsigned short* __restrict__ pk1,  // [2][8][64][8]
                      const unsigned short* __restrict__ pk3,  // [4][8][64][8]
                      const float* __restrict__ bmsg, const float* __restrict__ be2,
                      float* __restrict__ agg)
{
    __shared__ unsigned short s_t[EB * 128];  // 16 KB, swizzled
    __shared__ float s_d[EB];
    __shared__ int s_row[EB], s_col[EB];
    __shared__ int s_rs[EB + 1];
    __shared__ int s_nr;

    const int tid = threadIdx.x;
    const int w = tid >> 6;
    const int lane = tid & 63;
    const int lo = lane & 15, hi = lane >> 4;
    const int e0 = blockIdx.x * EB;
    const int colbase = w * 32;

    if (tid < EB) {
        s_d[tid] = sdist[e0 + tid];
        s_row[tid] = srow[e0 + tid];
        s_col[tid] = scol[e0 + tid];
    }
    __syncthreads();

    if (w == 0) {
        int c = s_col[lane];
        bool flag = (lane == 0) || (c != s_col[lane - 1]);
        unsigned long long m = __ballot(flag);
        if (flag) {
            int rank = __popcll(m & ((1ull << lane) - 1ull));
            s_rs[rank] = lane;
        }
        if (lane == 0) {
            int nr = __popcll(m);
            s_nr = nr;
            s_rs[nr] = EB;
        }
    }

    // ---- phase 1: C1 = RBF @ Wc  (K = 64)
    f32x4 acc[4][2];
#pragma unroll
    for (int rb = 0; rb < 4; ++rb)
#pragma unroll
        for (int cb = 0; cb < 2; ++cb) acc[rb][cb] = (f32x4){0.f, 0.f, 0.f, 0.f};

    float dv[4];
#pragma unroll
    for (int rb = 0; rb < 4; ++rb) dv[rb] = s_d[rb * 16 + lo];

    const float step = 6.0f / 63.0f;
#pragma unroll
    for (int kc = 0; kc < 2; ++kc) {
        bf16x8 a[4];
#pragma unroll
        for (int rb = 0; rb < 4; ++rb) {
            union { bf16x8 v; unsigned short u[8]; } U;
#pragma unroll
            for (int j = 0; j < 8; ++j) {
                float cc = (float)(kc * 32 + hi * 8 + j) * step;
                float t = dv[rb] - cc;
                U.u[j] = f2bf(__expf(-10.0f * t * t));
            }
            a[rb] = U.v;
        }
#pragma unroll
        for (int cb = 0; cb < 2; ++cb) {
            bf16x8 b = *reinterpret_cast<const bf16x8*>(
                pk1 + ((size_t)((kc * 8 + w * 2 + cb) * 64 + lane)) * 8);
#pragma unroll
            for (int rb = 0; rb < 4; ++rb)
                acc[rb][cb] = __builtin_amdgcn_mfma_f32_16x16x32_bf16(a[rb], b, acc[rb][cb], 0, 0, 0);
        }
    }

    // ---- phase 2: t = silu(C1 + P[col] + Q[row] + bmsg) -> bf16 LDS
    float bm[2];
#pragma unroll
    for (int cb = 0; cb < 2; ++cb) bm[cb] = bmsg[colbase + cb * 16 + lo];

#pragma unroll
    for (int rb = 0; rb < 4; ++rb) {
#pragma unroll
        for (int r = 0; r < 4; ++r) {
            int e = rb * 16 + hi * 4 + r;
            int nc = s_col[e], nrw = s_row[e];
#pragma unroll
            for (int cb = 0; cb < 2; ++cb) {
                int c = colbase + cb * 16 + lo;
                float v = acc[rb][cb][r] + P[(size_t)nc * 128 + c] + Q[(size_t)nrw * 128 + c] + bm[cb];
                float t = silu1(v);
                int byte = e * 256 + ((c * 2) ^ ((e & 7) << 4));
                *(unsigned short*)((char*)s_t + byte) = f2bf(t);
            }
        }
    }
    __syncthreads();

    // ---- phase 3: M = T @ We2  (K = 128)
    f32x4 acc2[4][2];
#pragma unroll
    for (int rb = 0; rb < 4; ++rb)
#pragma unroll
        for (int cb = 0; cb < 2; ++cb) acc2[rb][cb] = (f32x4){0.f, 0.f, 0.f, 0.f};

#pragma unroll
    for (int kc = 0; kc < 4; ++kc) {
        bf16x8 a[4];
#pragma unroll
        for (int rb = 0; rb < 4; ++rb) {
            int row = rb * 16 + lo;
            int byte = row * 256 + ((kc * 64 + hi * 16) ^ ((row & 7) << 4));
            a[rb] = *reinterpret_cast<const bf16x8*>((const char*)s_t + byte);
        }
#pragma unroll
        for (int cb = 0; cb < 2; ++cb) {
            bf16x8 b = *reinterpret_cast<const bf16x8*>(
                pk3 + ((size_t)((kc * 8 + w * 2 + cb) * 64 + lane)) * 8);
#pragma unroll
            for (int rb = 0; rb < 4; ++rb)
                acc2[rb][cb] = __builtin_amdgcn_mfma_f32_16x16x32_bf16(a[rb], b, acc2[rb][cb], 0, 0, 0);
        }
    }

    // ---- phase 4: per-run reduce + atomicAdd (+ run_len * be2)
    float be2c[2];
#pragma unroll
    for (int cb = 0; cb < 2; ++cb) be2c[cb] = be2[colbase + cb * 16 + lo];

    int nruns = s_nr;
    for (int ri = 0; ri < nruns; ++ri) {
        int a0 = s_rs[ri], b0 = s_rs[ri + 1];
        int node = s_col[a0];
        float s0 = 0.f, s1 = 0.f;
#pragma unroll
        for (int rb = 0; rb < 4; ++rb)
#pragma unroll
            for (int r = 0; r < 4; ++r) {
                int e = rb * 16 + hi * 4 + r;
                bool in = (e >= a0) && (e < b0);
                s0 += in ? acc2[rb][0][r] : 0.f;
                s1 += in ? acc2[rb][1][r] : 0.f;
            }
        s0 += __shfl_xor(s0, 16, 64); s0 += __shfl_xor(s0, 32, 64);
        s1 += __shfl_xor(s1, 16, 64); s1 += __shfl_xor(s1, 32, 64);
        if (hi == 0) {
            float len = (float)(b0 - a0);
            atomicAdd(agg + (size_t)node * 128 + colbase + lo, s0 + len * be2c[0]);
            atomicAdd(agg + (size_t)node * 128 + colbase + 16 + lo, s1 + len * be2c[1]);
        }
    }
}

// ---------------------------------------------------------------------------
// MFMA node update, split-precision A AND B (3-term), both stages:
//   X_out = silu(agg @ W_u1 + b_u1) @ W_u2 + b_u2
// ---------------------------------------------------------------------------
__global__ __launch_bounds__(256, 2)
void nodeupd_kernel(const float* __restrict__ AGG,
                    const unsigned short* __restrict__ pku1h,
                    const unsigned short* __restrict__ pku1l,
                    const float* __restrict__ bu1,
                    const unsigned short* __restrict__ pku2h,
                    const unsigned short* __restrict__ pku2l,
                    const float* __restrict__ bu2,
                    float* __restrict__ Xout)
{
    __shared__ unsigned short s_h[64 * 128];  // 16 KB, swizzled (hi)
    __shared__ unsigned short s_l[64 * 128];  // 16 KB, swizzled (lo)

    const int tid = threadIdx.x;
    const int w = tid >> 6;
    const int lane = tid & 63;
    const int lo = lane & 15, hi = lane >> 4;
    const int r0 = blockIdx.x * 64;
    const int colbase = w * 32;

    // stage agg tile -> hi/lo bf16 swizzled LDS
    for (int i = tid; i < 1024; i += 256) {
        int e = i >> 4, cg = i & 15;
        int r = r0 + e;
        union { unsigned short u16[8]; f4 v; } H, L;
        if (r < NN) {
            f4 v0 = ((const f4*)AGG)[(size_t)r * 32 + cg * 2];
            f4 v1 = ((const f4*)AGG)[(size_t)r * 32 + cg * 2 + 1];
#pragma unroll
            for (int q = 0; q < 4; ++q) {
                unsigned short h0 = f2bf(v0[q]);
                unsigned short h1 = f2bf(v1[q]);
                H.u16[q] = h0;     L.u16[q] = f2bf(v0[q] - bf2f(h0));
                H.u16[4 + q] = h1; L.u16[4 + q] = f2bf(v1[q] - bf2f(h1));
            }
        } else {
#pragma unroll
            for (int q = 0; q < 8; ++q) { H.u16[q] = 0; L.u16[q] = 0; }
        }
        int byte = e * 256 + ((cg * 16) ^ ((e & 7) << 4));
        *reinterpret_cast<f4*>((char*)s_h + byte) = H.v;
        *reinterpret_cast<f4*>((char*)s_l + byte) = L.v;
    }
    __syncthreads();

    // ---- stage 1: t = silu(agg @ Wu1 + b1)
    f32x4 acc[4][2];
#pragma unroll
    for (int rb = 0; rb < 4; ++rb)
#pragma unroll
        for (int cb = 0; cb < 2; ++cb) acc[rb][cb] = (f32x4){0.f, 0.f, 0.f, 0.f};

#pragma unroll
    for (int kc = 0; kc < 4; ++kc) {
        bf16x8 ah[4], al[4];
#pragma unroll
        for (int rb = 0; rb < 4; ++rb) {
            int row = rb * 16 + lo;
            int byte = row * 256 + ((kc * 64 + hi * 16) ^ ((row & 7) << 4));
            ah[rb] = *reinterpret_cast<const bf16x8*>((const char*)s_h + byte);
            al[rb] = *reinterpret_cast<const bf16x8*>((const char*)s_l + byte);
        }
#pragma unroll
        for (int cb = 0; cb < 2; ++cb) {
            size_t boff = ((size_t)((kc * 8 + w * 2 + cb) * 64 + lane)) * 8;
            bf16x8 bh = *reinterpret_cast<const bf16x8*>(pku1h + boff);
            bf16x8 bl = *reinterpret_cast<const bf16x8*>(pku1l + boff);
#pragma unroll
            for (int rb = 0; rb < 4; ++rb) {
                acc[rb][cb] = __builtin_amdgcn_mfma_f32_16x16x32_bf16(ah[rb], bh, acc[rb][cb], 0, 0, 0);
                acc[rb][cb] = __builtin_amdgcn_mfma_f32_16x16x32_bf16(al[rb], bh, acc[rb][cb], 0, 0, 0);
                acc[rb][cb] = __builtin_amdgcn_mfma_f32_16x16x32_bf16(ah[rb], bl, acc[rb][cb], 0, 0, 0);
            }
        }
    }

    float b1c[2];
#pragma unroll
    for (int cb = 0; cb < 2; ++cb) b1c[cb] = bu1[colbase + cb * 16 + lo];

    __syncthreads();  // all stage-1 LDS reads complete before overwrite

#pragma unroll
    for (int rb = 0; rb < 4; ++rb)
#pragma unroll
        for (int r = 0; r < 4; ++r) {
            int row = rb * 16 + hi * 4 + r;
#pragma unroll
            for (int cb = 0; cb < 2; ++cb) {
                int col = colbase + cb * 16 + lo;
                float t = silu1(acc[rb][cb][r] + b1c[cb]);
                unsigned short th = f2bf(t);
                unsigned short tl = f2bf(t - bf2f(th));
                int byte = row * 256 + ((col * 2) ^ ((row & 7) << 4));
                *(unsigned short*)((char*)s_h + byte) = th;
                *(unsigned short*)((char*)s_l + byte) = tl;
            }
        }
    __syncthreads();

    // ---- stage 2: X_out = t @ Wu2 + b2
    f32x4 acc2[4][2];
#pragma unroll
    for (int rb = 0; rb < 4; ++rb)
#pragma unroll
        for (int cb = 0; cb < 2; ++cb) acc2[rb][cb] = (f32x4){0.f, 0.f, 0.f, 0.f};

#pragma unroll
    for (int kc = 0; kc < 4; ++kc) {
        bf16x8 ah[4], al[4];
#pragma unroll
        for (int rb = 0; rb < 4; ++rb) {
            int row = rb * 16 + lo;
            int byte = row * 256 + ((kc * 64 + hi * 16) ^ ((row & 7) << 4));
            ah[rb] = *reinterpret_cast<const bf16x8*>((const char*)s_h + byte);
            al[rb] = *reinterpret_cast<const bf16x8*>((const char*)s_l + byte);
        }
#pragma unroll
        for (int cb = 0; cb < 2; ++cb) {
            size_t boff = ((size_t)((kc * 8 + w * 2 + cb) * 64 + lane)) * 8;
            bf16x8 bh = *reinterpret_cast<const bf16x8*>(pku2h + boff);
            bf16x8 bl = *reinterpret_cast<const bf16x8*>(pku2l + boff);
#pragma unroll
            for (int rb = 0; rb < 4; ++rb) {
                acc2[rb][cb] = __builtin_amdgcn_mfma_f32_16x16x32_bf16(ah[rb], bh, acc2[rb][cb], 0, 0, 0);
                acc2[rb][cb] = __builtin_amdgcn_mfma_f32_16x16x32_bf16(al[rb], bh, acc2[rb][cb], 0, 0, 0);
                acc2[rb][cb] = __builtin_amdgcn_mfma_f32_16x16x32_bf16(ah[rb], bl, acc2[rb][cb], 0, 0, 0);
            }
        }
    }

    float b2c[2];
#pragma unroll
    for (int cb = 0; cb < 2; ++cb) b2c[cb] = bu2[colbase + cb * 16 + lo];

#pragma unroll
    for (int rb = 0; rb < 4; ++rb)
#pragma unroll
        for (int r = 0; r < 4; ++r) {
            int row = r0 + rb * 16 + hi * 4 + r;
            if (row < NN) {
#pragma unroll
                for (int cb = 0; cb < 2; ++cb) {
                    int col = colbase + cb * 16 + lo;
                    Xout[(size_t)row * 128 + col] = acc2[rb][cb][r] + b2c[cb];
                }
            }
        }
}

// ---------------------------------------------------------------------------
// Graph readout: grid (G, 4); block reduces 32 cols of one graph segment
// ---------------------------------------------------------------------------
__global__ void gsum2_kernel(const float* __restrict__ X, const int* __restrict__ gstart,
                             float* __restrict__ Gm)
{
    __shared__ f4 red[32][8];
    int g = blockIdx.x;
    int q = blockIdx.y;
    int cq = threadIdx.x & 7;
    int cf = q * 8 + cq;          // f4 col (0..31)
    int rg = threadIdx.x >> 3;    // 0..31
    int i0 = gstart[g], i1 = gstart[g + 1];
    f4 s = {0.f, 0.f, 0.f, 0.f};
    for (int i = i0 + rg; i < i1; i += 32)
        s += ((const f4*)X)[(size_t)i * 32 + cf];
    red[rg][cq] = s;
    __syncthreads();
    for (int off = 16; off >= 1; off >>= 1) {
        if (rg < off) red[rg][cq] += red[rg + off][cq];
        __syncthreads();
    }
    if (rg == 0) ((f4*)Gm)[g * 32 + cf] = red[0][cq];
}

__global__ void final_kernel(const float* __restrict__ Gm,
                             const float* __restrict__ Wf1, const float* __restrict__ bf1,
                             const float* __restrict__ Wf2, const float* __restrict__ bf2,
                             float* __restrict__ out)
{
    __shared__ float red[128];
    int g = blockIdx.x;
    int j = threadIdx.x;
    float s = bf1[j];
    for (int k = 0; k < 128; ++k) s += Gm[(size_t)g * 128 + k] * Wf1[k * 128 + j];
    s = silu1(s);
    red[j] = s * Wf2[j];
    __syncthreads();
    for (int off = 64; off > 0; off >>= 1) {
        if (j < off) red[j] += red[j + off];
        __syncthreads();
    }
    if (j == 0) out[g] = red[0] + bf2[0];
}

// ---------------------------------------------------------------------------
extern "C" void kernel_launch(void* const* d_in, const int* in_sizes, int n_in,
                              void* d_out, int out_size, void* d_ws, size_t ws_size,
                              hipStream_t stream)
{
    const float* x     = (const float*)d_in[0];
    const float* pos   = (const float*)d_in[1];
    const int*   eidx  = (const int*)d_in[2];
    const int*   batch = (const int*)d_in[3];
    const float* Wnode = (const float*)d_in[4];
    const float* bnode = (const float*)d_in[5];
    const float* Wrbf  = (const float*)d_in[6];
    const float* brbf  = (const float*)d_in[7];
    const float* We1   = (const float*)d_in[8];
    const float* be1   = (const float*)d_in[9];
    const float* We2   = (const float*)d_in[10];
    const float* be2   = (const float*)d_in[11];
    const float* Wu1   = (const float*)d_in[12];
    const float* bu1   = (const float*)d_in[13];
    const float* Wu2   = (const float*)d_in[14];
    const float* bu2   = (const float*)d_in[15];
    const float* Wf1   = (const float*)d_in[16];
    const float* bf1   = (const float*)d_in[17];
    const float* Wf2   = (const float*)d_in[18];
    const float* bf2   = (const float*)d_in[19];

    const int* erow = eidx;
    const int* ecol = eidx + NE;

    char* wsb = (char*)d_ws;
    size_t off = 0;
    auto take = [&](size_t bytes) -> char* {
        char* p = wsb + off;
        off += (bytes + 255) & ~(size_t)255;
        return p;
    };
    float* Pb    = (float*)take((size_t)NN * HH * 4);
    float* Qb    = (float*)take((size_t)NN * HH * 4);
    float* aggb  = (float*)take((size_t)NN * HH * 4);
    float* xa    = (float*)take((size_t)NN * DD * 4);
    float* gm    = (float*)take((size_t)GG * DD * 4);
    float* Wpa   = (float*)take((size_t)LL * DD * HH * 4);
    float* Wqb   = (float*)take((size_t)LL * DD * HH * 4);
    float* Wcc   = (float*)take((size_t)LL * RR * HH * 4);
    float* bmsg  = (float*)take((size_t)LL * HH * 4);
    int*   cnt   = (int*)take((size_t)NN * 4);
    int*   cur   = (int*)take((size_t)NN * 4);
    int*   srow  = (int*)take((size_t)NE * 4);
    int*   scol  = (int*)take((size_t)NE * 4);
    float* sdist = (float*)take((size_t)NE * 4);
    int*   gst   = (int*)take((size_t)(GG + 1) * 4);
    unsigned short* pk1   = (unsigned short*)take((size_t)LL * RR * HH * 2);
    unsigned short* pk3   = (unsigned short*)take((size_t)LL * HH * HH * 2);
    unsigned short* pkpah = (unsigned short*)take((size_t)LL * DD * HH * 2);
    unsigned short* pkpal = (unsigned short*)take((size_t)LL * DD * HH * 2);
    unsigned short* pkqbh = (unsigned short*)take((size_t)LL * DD * HH * 2);
    unsigned short* pkqbl = (unsigned short*)take((size_t)LL * DD * HH * 2);
    unsigned short* pku1h = (unsigned short*)take((size_t)LL * HH * HH * 2);
    unsigned short* pku1l = (unsigned short*)take((size_t)LL * HH * HH * 2);
    unsigned short* pku2h = (unsigned short*)take((size_t)LL * HH * DD * 2);
    unsigned short* pku2l = (unsigned short*)take((size_t)LL * HH * DD * 2);

    if (off > ws_size) return;  // fail loudly (absmax), not a fault

    // ---- one-time preprocessing
    fillz_kernel<<<(NN + 1023) / 1024, 256, 0, stream>>>((float*)cnt, NN / 4);
    hist_kernel<<<(NE + 255) / 256, 256, 0, stream>>>(ecol, cnt);
    scan_kernel<<<1, 1024, 0, stream>>>(cnt, cur);
    scatter_kernel<<<(NE + 255) / 256, 256, 0, stream>>>(pos, erow, ecol, cur, srow, scol, sdist);
    gstart_kernel<<<(NN + 255) / 256, 256, 0, stream>>>(batch, gst);

    fold_kernel<<<LL * 4, 256, 0, stream>>>(Wnode, Wrbf, We1, bnode, brbf, be1,
                                            Wpa, Wqb, Wcc, bmsg);
    for (int l = 0; l < LL; ++l) {
        pack_kernel<<<(RR * HH + 255) / 256, 256, 0, stream>>>(
            Wcc + (size_t)l * RR * HH, pk1 + (size_t)l * RR * HH, RR);
        pack_kernel<<<(HH * HH + 255) / 256, 256, 0, stream>>>(
            We2 + (size_t)l * HH * HH, pk3 + (size_t)l * HH * HH, HH);
        pack2_kernel<<<(DD * HH + 255) / 256, 256, 0, stream>>>(
            Wpa + (size_t)l * DD * HH, pkpah + (size_t)l * DD * HH,
            pkpal + (size_t)l * DD * HH, DD);
        pack2_kernel<<<(DD * HH + 255) / 256, 256, 0, stream>>>(
            Wqb + (size_t)l * DD * HH, pkqbh + (size_t)l * DD * HH,
            pkqbl + (size_t)l * DD * HH, DD);
        pack2_kernel<<<(HH * HH + 255) / 256, 256, 0, stream>>>(
            Wu1 + (size_t)l * HH * HH, pku1h + (size_t)l * HH * HH,
            pku1l + (size_t)l * HH * HH, HH);
        pack2_kernel<<<(HH * DD + 255) / 256, 256, 0, stream>>>(
            Wu2 + (size_t)l * HH * DD, pku2h + (size_t)l * HH * DD,
            pku2l + (size_t)l * HH * DD, HH);
    }

    // ---- layers
    const int nblk = (NN + 63) / 64;
    const float* xin = x;
    for (int l = 0; l < LL; ++l) {
        nodepq_kernel<<<nblk, 256, 0, stream>>>(xin,
                                                pkpah + (size_t)l * DD * HH,
                                                pkpal + (size_t)l * DD * HH,
                                                pkqbh + (size_t)l * DD * HH,
                                                pkqbl + (size_t)l * DD * HH,
                                                Pb, Qb, aggb);
        edge_mfma_kernel<<<NE / EB, 256, 0, stream>>>(Pb, Qb, sdist, srow, scol,
                                                      pk1 + (size_t)l * RR * HH,
                                                      pk3 + (size_t)l * HH * HH,
                                                      bmsg + (size_t)l * HH,
                                                      be2 + (size_t)l * HH, aggb);
        nodeupd_kernel<<<nblk, 256, 0, stream>>>(aggb,
                                                 pku1h + (size_t)l * HH * HH,
                                                 pku1l + (size_t)l * HH * HH,
                                                 bu1 + (size_t)l * HH,
                                                 pku2h + (size_t)l * HH * DD,
                                                 pku2l + (size_t)l * HH * DD,
                                                 bu2 + (size_t)l * DD, xa);
        xin = xa;
    }

    dim3 gsgrid(GG, 4);
    gsum2_kernel<<<gsgrid, 256, 0, stream>>>(xin, gst, gm);
    final_kernel<<<GG, 128, 0, stream>>>(gm, Wf1, bf1, Wf2, bf2, (float*)d_out);
}

// Round 7
// 1021.208 us; speedup vs baseline: 6.3187x; 1.1818x over previous
//
#include <hip/hip_runtime.h>

#define NN 50000   // nodes
#define NE 800000  // edges
#define DD 128     // node dim
#define HH 128     // hidden dim
#define RR 64      // num rbf
#define LL 4       // layers
#define GG 64      // graphs
#define EB 64      // edges per block (edge kernel)

typedef float f4 __attribute__((ext_vector_type(4)));
typedef __attribute__((ext_vector_type(8))) short bf16x8;  // MFMA A/B frag (4 VGPR)
typedef __attribute__((ext_vector_type(4))) float f32x4;   // MFMA C/D frag

__device__ __forceinline__ float silu1(float v) { return v / (1.0f + __expf(-v)); }

// RNE float -> bf16 bits (branchless; inputs finite)
__device__ __forceinline__ unsigned short f2bf(float f)
{
    union { float f; unsigned u; } x; x.f = f;
    unsigned r = x.u + 0x7fffu + ((x.u >> 16) & 1u);
    return (unsigned short)(r >> 16);
}
__device__ __forceinline__ float bf2f(unsigned short h)
{
    union { unsigned u; float f; } x; x.u = ((unsigned)h) << 16; return x.f;
}

// ---------------------------------------------------------------------------
// Zero fill
// ---------------------------------------------------------------------------
__global__ void fillz_kernel(float* __restrict__ p, int n4)
{
    int i = blockIdx.x * 256 + threadIdx.x;
    if (i < n4) ((f4*)p)[i] = (f4){0.f, 0.f, 0.f, 0.f};
}

// ---------------------------------------------------------------------------
// Counting sort of edges by col (destination). One-time per call.
// ---------------------------------------------------------------------------
__global__ void hist_kernel(const int* __restrict__ ecol, int* __restrict__ cnt)
{
    int e = blockIdx.x * 256 + threadIdx.x;
    if (e < NE) atomicAdd(&cnt[ecol[e]], 1);
}

__global__ void scan_kernel(const int* __restrict__ cnt, int* __restrict__ cur)
{
    __shared__ int s[1024];
    int t = threadIdx.x;               // 1024 threads, 1 block
    const int CH = 49;                 // 1024*49 = 50176 >= NN
    int a0 = t * CH, a1 = a0 + CH; if (a1 > NN) a1 = NN; if (a0 > NN) a0 = NN;
    int s0 = 0;
    for (int i = a0; i < a1; ++i) s0 += cnt[i];
    s[t] = s0;
    __syncthreads();
    for (int off = 1; off < 1024; off <<= 1) {
        int v = (t >= off) ? s[t - off] : 0;
        __syncthreads();
        s[t] += v;
        __syncthreads();
    }
    int base = (t == 0) ? 0 : s[t - 1];
    for (int i = a0; i < a1; ++i) { cur[i] = base; base += cnt[i]; }
}

__global__ void scatter_kernel(const float* __restrict__ pos,
                               const int* __restrict__ erow, const int* __restrict__ ecol,
                               int* __restrict__ cur,
                               int* __restrict__ srow, int* __restrict__ scol,
                               float* __restrict__ sdist)
{
    int e = blockIdx.x * 256 + threadIdx.x;
    if (e >= NE) return;
    int r = erow[e], c = ecol[e];
    int p = atomicAdd(&cur[c], 1);
    srow[p] = r;
    scol[p] = c;
    float dx = pos[r * 3 + 0] - pos[c * 3 + 0];
    float dy = pos[r * 3 + 1] - pos[c * 3 + 1];
    float dz = pos[r * 3 + 2] - pos[c * 3 + 2];
    sdist[p] = sqrtf(dx * dx + dy * dy + dz * dz);
}

// ---------------------------------------------------------------------------
// Graph segment boundaries from sorted batch
// ---------------------------------------------------------------------------
__global__ void gstart_kernel(const int* __restrict__ batch, int* __restrict__ gstart)
{
    int i = blockIdx.x * 256 + threadIdx.x;
    if (i >= NN) return;
    int b = batch[i];
    if (i == 0) {
        for (int g = 0; g <= b; ++g) gstart[g] = 0;
    } else {
        int bp = batch[i - 1];
        for (int g = bp + 1; g <= b; ++g) gstart[g] = i;
    }
    if (i == NN - 1) {
        for (int g = b + 1; g <= GG; ++g) gstart[g] = NN;
    }
}

// ---------------------------------------------------------------------------
// Weight folding (fp32), parallel: one thread per output element.
// Per layer: Wpa (16384) | Wqb (16384) | Wc (8192) | bmsg (128) = 41088 elems.
// grid = (161, L)
// ---------------------------------------------------------------------------
__global__ void fold_kernel(const float* __restrict__ Wnode, const float* __restrict__ Wrbf,
                            const float* __restrict__ We1,
                            const float* __restrict__ bnode, const float* __restrict__ brbf,
                            const float* __restrict__ be1,
                            float* __restrict__ Wpa, float* __restrict__ Wqb,
                            float* __restrict__ Wc, float* __restrict__ bmsg)
{
    int l = blockIdx.y;
    int o = blockIdx.x * 256 + threadIdx.x;
    const float* We1l = We1 + (size_t)l * 384 * 128;
    if (o < 16384) {
        int r = o >> 7, c = o & 127;
        const float* A = Wnode + (size_t)l * 16384;
        float s = 0.f;
        for (int k = 0; k < 128; ++k) s += A[r * 128 + k] * We1l[k * 128 + c];
        Wpa[(size_t)l * 16384 + o] = s;
    } else if (o < 32768) {
        int oo = o - 16384;
        int r = oo >> 7, c = oo & 127;
        const float* A = Wnode + (size_t)l * 16384;
        const float* B = We1l + 16384;
        float s = 0.f;
        for (int k = 0; k < 128; ++k) s += A[r * 128 + k] * B[k * 128 + c];
        Wqb[(size_t)l * 16384 + oo] = s;
    } else if (o < 40960) {
        int oo = o - 32768;
        int r = oo >> 7, c = oo & 127;
        const float* A = Wrbf + (size_t)l * 8192;
        const float* B = We1l + 32768;
        float s = 0.f;
        for (int k = 0; k < 128; ++k) s += A[r * 128 + k] * B[k * 128 + c];
        Wc[(size_t)l * 8192 + oo] = s;
    } else if (o < 41088) {
        int j = o - 40960;
        float s = be1[l * 128 + j];
        for (int k = 0; k < 128; ++k) {
            float w = We1l[k * 128 + j] + We1l[(128 + k) * 128 + j];
            s += bnode[l * 128 + k] * w + brbf[l * 128 + k] * We1l[(256 + k) * 128 + j];
        }
        bmsg[l * 128 + j] = s;
    }
}

// ---------------------------------------------------------------------------
// Pack fp32 weight M[K][128] into per-lane MFMA B-fragment order, bf16
// ---------------------------------------------------------------------------
__global__ void pack_kernel(const float* __restrict__ M, unsigned short* __restrict__ pk, int K)
{
    int idx = blockIdx.x * 256 + threadIdx.x;
    if (idx >= K * 128) return;
    int k = idx >> 7, c = idx & 127;
    int kc = k >> 5, hi = (k >> 3) & 3, j = k & 7;
    int cbG = c >> 4, lo = c & 15;
    int lane = hi * 16 + lo;
    pk[(((kc * 8 + cbG) * 64 + lane) * 8) + j] = f2bf(M[idx]);
}

// Same, but hi/lo split pair (for node-path weights: removes B-quant error)
__global__ void pack2_kernel(const float* __restrict__ M,
                             unsigned short* __restrict__ pkh,
                             unsigned short* __restrict__ pkl, int K)
{
    int idx = blockIdx.x * 256 + threadIdx.x;
    if (idx >= K * 128) return;
    int k = idx >> 7, c = idx & 127;
    int kc = k >> 5, hi = (k >> 3) & 3, j = k & 7;
    int cbG = c >> 4, lo = c & 15;
    int lane = hi * 16 + lo;
    int o = (((kc * 8 + cbG) * 64 + lane) * 8) + j;
    float v = M[idx];
    unsigned short h = f2bf(v);
    pkh[o] = h;
    pkl[o] = f2bf(v - bf2f(h));
}

// ---------------------------------------------------------------------------
// MFMA dual node GEMM, split-precision A AND B (3-term products):
//   P = X @ Wpa, Q = X @ Wqb; also zeroes agg rows.
// ---------------------------------------------------------------------------
__global__ __launch_bounds__(256, 2)
void nodepq_kernel(const float* __restrict__ X,
                   const unsigned short* __restrict__ pkpah,
                   const unsigned short* __restrict__ pkpal,
                   const unsigned short* __restrict__ pkqbh,
                   const unsigned short* __restrict__ pkqbl,
                   float* __restrict__ P, float* __restrict__ Q,
                   float* __restrict__ agg)
{
    __shared__ unsigned short s_h[64 * 128];  // 16 KB, swizzled (hi)
    __shared__ unsigned short s_l[64 * 128];  // 16 KB, swizzled (lo)

    const int tid = threadIdx.x;
    const int w = tid >> 6;
    const int lane = tid & 63;
    const int lo = lane & 15, hi = lane >> 4;
    const int r0 = blockIdx.x * 64;
    const int colbase = w * 32;

    for (int i = tid; i < 1024; i += 256) {
        int e = i >> 4, cg = i & 15;
        int r = r0 + e;
        union { unsigned short u16[8]; f4 v; } H, L;
        if (r < NN) {
            f4 v0 = ((const f4*)X)[(size_t)r * 32 + cg * 2];
            f4 v1 = ((const f4*)X)[(size_t)r * 32 + cg * 2 + 1];
#pragma unroll
            for (int q = 0; q < 4; ++q) {
                unsigned short h0 = f2bf(v0[q]);
                unsigned short h1 = f2bf(v1[q]);
                H.u16[q] = h0;     L.u16[q] = f2bf(v0[q] - bf2f(h0));
                H.u16[4 + q] = h1; L.u16[4 + q] = f2bf(v1[q] - bf2f(h1));
            }
        } else {
#pragma unroll
            for (int q = 0; q < 8; ++q) { H.u16[q] = 0; L.u16[q] = 0; }
        }
        int byte = e * 256 + ((cg * 16) ^ ((e & 7) << 4));
        *reinterpret_cast<f4*>((char*)s_h + byte) = H.v;
        *reinterpret_cast<f4*>((char*)s_l + byte) = L.v;
    }
    for (int i = tid; i < 2048; i += 256) {
        int e = i >> 5, cc = i & 31;
        int r = r0 + e;
        if (r < NN) ((f4*)agg)[(size_t)r * 32 + cc] = (f4){0.f, 0.f, 0.f, 0.f};
    }
    __syncthreads();

    f32x4 accp[4][2], accq[4][2];
#pragma unroll
    for (int rb = 0; rb < 4; ++rb)
#pragma unroll
        for (int cb = 0; cb < 2; ++cb) {
            accp[rb][cb] = (f32x4){0.f, 0.f, 0.f, 0.f};
            accq[rb][cb] = (f32x4){0.f, 0.f, 0.f, 0.f};
        }

#pragma unroll
    for (int kc = 0; kc < 4; ++kc) {
        bf16x8 ah[4], al[4];
#pragma unroll
        for (int rb = 0; rb < 4; ++rb) {
            int row = rb * 16 + lo;
            int byte = row * 256 + ((kc * 64 + hi * 16) ^ ((row & 7) << 4));
            ah[rb] = *reinterpret_cast<const bf16x8*>((const char*)s_h + byte);
            al[rb] = *reinterpret_cast<const bf16x8*>((const char*)s_l + byte);
        }
#pragma unroll
        for (int cb = 0; cb < 2; ++cb) {
            size_t boff = ((size_t)((kc * 8 + w * 2 + cb) * 64 + lane)) * 8;
            bf16x8 bph = *reinterpret_cast<const bf16x8*>(pkpah + boff);
            bf16x8 bpl = *reinterpret_cast<const bf16x8*>(pkpal + boff);
            bf16x8 bqh = *reinterpret_cast<const bf16x8*>(pkqbh + boff);
            bf16x8 bql = *reinterpret_cast<const bf16x8*>(pkqbl + boff);
#pragma unroll
            for (int rb = 0; rb < 4; ++rb) {
                accp[rb][cb] = __builtin_amdgcn_mfma_f32_16x16x32_bf16(ah[rb], bph, accp[rb][cb], 0, 0, 0);
                accp[rb][cb] = __builtin_amdgcn_mfma_f32_16x16x32_bf16(al[rb], bph, accp[rb][cb], 0, 0, 0);
                accp[rb][cb] = __builtin_amdgcn_mfma_f32_16x16x32_bf16(ah[rb], bpl, accp[rb][cb], 0, 0, 0);
                accq[rb][cb] = __builtin_amdgcn_mfma_f32_16x16x32_bf16(ah[rb], bqh, accq[rb][cb], 0, 0, 0);
                accq[rb][cb] = __builtin_amdgcn_mfma_f32_16x16x32_bf16(al[rb], bqh, accq[rb][cb], 0, 0, 0);
                accq[rb][cb] = __builtin_amdgcn_mfma_f32_16x16x32_bf16(ah[rb], bql, accq[rb][cb], 0, 0, 0);
            }
        }
    }

#pragma unroll
    for (int rb = 0; rb < 4; ++rb)
#pragma unroll
        for (int r = 0; r < 4; ++r) {
            int row = r0 + rb * 16 + hi * 4 + r;
            if (row < NN) {
#pragma unroll
                for (int cb = 0; cb < 2; ++cb) {
                    int col = colbase + cb * 16 + lo;
                    P[(size_t)row * 128 + col] = accp[rb][cb][r];
                    Q[(size_t)row * 128 + col] = accq[rb][cb][r];
                }
            }
        }
}

// ---------------------------------------------------------------------------
// MFMA edge kernel, restructured: wave w owns 16 edges [16w,16w+16) x ALL 128
// cols (M=16 tile).  Kills RBF duplication (16 exps/thread) and shrinks the
// per-run reduce (runs clipped to the wave's 16-edge window).
// C/D layout: row(local edge)=(lane>>4)*4+reg, col=cb*16+(lane&15).
// ---------------------------------------------------------------------------
__global__ __launch_bounds__(256, 3)
void edge_mfma_kernel(const float* __restrict__ P, const float* __restrict__ Q,
                      const float* __restrict__ sdist,
                      const int* __restrict__ srow, const int* __restrict__ scol,
                      const unsigned short* __restrict__ pk1,  // [2][8][64][8]
                      const unsigned short* __restrict__ pk3,  // [4][8][64][8]
                      const float* __restrict__ bmsg, const float* __restrict__ be2,
                      float* __restrict__ agg)
{
    __shared__ unsigned short s_t[EB * 128];  // 16 KB, swizzled
    __shared__ float s_d[EB];
    __shared__ int s_row[EB], s_col[EB];
    __shared__ int s_rs[EB + 1];
    __shared__ int s_nr;

    const int tid = threadIdx.x;
    const int w = tid >> 6;
    const int lane = tid & 63;
    const int lo = lane & 15, hi = lane >> 4;
    const int e0 = blockIdx.x * EB;
    const int ew = w * 16;                    // wave's edge window [ew, ew+16)

    if (tid < EB) {
        s_d[tid] = sdist[e0 + tid];
        s_row[tid] = srow[e0 + tid];
        s_col[tid] = scol[e0 + tid];
    }
    __syncthreads();

    if (w == 0) {
        int c = s_col[lane];
        bool flag = (lane == 0) || (c != s_col[lane - 1]);
        unsigned long long m = __ballot(flag);
        if (flag) {
            int rank = __popcll(m & ((1ull << lane) - 1ull));
            s_rs[rank] = lane;
        }
        if (lane == 0) {
            int nr = __popcll(m);
            s_nr = nr;
            s_rs[nr] = EB;
        }
    }
    // (s_rs/s_nr visibility guaranteed by the barrier before phase 3)

    // ---- phase 1: C1 = RBF @ Wc  (K = 64); A row = local edge = lo
    f32x4 acc[8];
#pragma unroll
    for (int cb = 0; cb < 8; ++cb) acc[cb] = (f32x4){0.f, 0.f, 0.f, 0.f};

    const float dvv = s_d[ew + lo];
    const float step = 6.0f / 63.0f;
#pragma unroll
    for (int kc = 0; kc < 2; ++kc) {
        union { bf16x8 v; unsigned short u[8]; } U;
#pragma unroll
        for (int j = 0; j < 8; ++j) {
            float t = dvv - (float)(kc * 32 + hi * 8 + j) * step;
            U.u[j] = f2bf(__expf(-10.0f * t * t));
        }
#pragma unroll
        for (int cb = 0; cb < 8; ++cb) {
            bf16x8 b = *reinterpret_cast<const bf16x8*>(
                pk1 + ((size_t)((kc * 8 + cb) * 64 + lane)) * 8);
            acc[cb] = __builtin_amdgcn_mfma_f32_16x16x32_bf16(U.v, b, acc[cb], 0, 0, 0);
        }
    }

    // ---- phase 2: t = silu(C1 + P[col] + Q[row] + bmsg) -> bf16 LDS
    float bm[8];
#pragma unroll
    for (int cb = 0; cb < 8; ++cb) bm[cb] = bmsg[cb * 16 + lo];

#pragma unroll
    for (int r = 0; r < 4; ++r) {
        int e = ew + hi * 4 + r;
        int nc = s_col[e], nrw = s_row[e];
        const float* Prow = P + (size_t)nc * 128;
        const float* Qrow = Q + (size_t)nrw * 128;
        int sw = (e & 7) << 4;
#pragma unroll
        for (int cb = 0; cb < 8; ++cb) {
            int c = cb * 16 + lo;
            float v = acc[cb][r] + Prow[c] + Qrow[c] + bm[cb];
            float t = silu1(v);
            int byte = e * 256 + ((c * 2) ^ sw);
            *(unsigned short*)((char*)s_t + byte) = f2bf(t);
        }
    }
    __syncthreads();

    // ---- phase 3: M = T @ We2  (K = 128); A row = ew + lo
    f32x4 acc2[8];
#pragma unroll
    for (int cb = 0; cb < 8; ++cb) acc2[cb] = (f32x4){0.f, 0.f, 0.f, 0.f};

    {
        const int rowA = ew + lo;
        const int swA = (rowA & 7) << 4;
#pragma unroll
        for (int kc = 0; kc < 4; ++kc) {
            bf16x8 a = *reinterpret_cast<const bf16x8*>(
                (const char*)s_t + rowA * 256 + ((kc * 64 + hi * 16) ^ swA));
#pragma unroll
            for (int cb = 0; cb < 8; ++cb) {
                bf16x8 b = *reinterpret_cast<const bf16x8*>(
                    pk3 + ((size_t)((kc * 8 + cb) * 64 + lane)) * 8);
                acc2[cb] = __builtin_amdgcn_mfma_f32_16x16x32_bf16(a, b, acc2[cb], 0, 0, 0);
            }
        }
    }

    // ---- phase 4: per-run reduce clipped to this wave's window + atomicAdd
    float be2c[8];
#pragma unroll
    for (int cb = 0; cb < 8; ++cb) be2c[cb] = be2[cb * 16 + lo];

    int nruns = s_nr;
    for (int ri = 0; ri < nruns; ++ri) {
        int a0 = s_rs[ri], b0 = s_rs[ri + 1];
        if (b0 <= ew || a0 >= ew + 16) continue;   // wave-uniform skip
        int la = a0 - ew; if (la < 0) la = 0;
        int lb = b0 - ew; if (lb > 16) lb = 16;
        int node = s_col[a0];
        float s[8];
#pragma unroll
        for (int cb = 0; cb < 8; ++cb) s[cb] = 0.f;
#pragma unroll
        for (int r = 0; r < 4; ++r) {
            int el = hi * 4 + r;
            bool in = (el >= la) && (el < lb);
#pragma unroll
            for (int cb = 0; cb < 8; ++cb)
                s[cb] += in ? acc2[cb][r] : 0.f;
        }
#pragma unroll
        for (int cb = 0; cb < 8; ++cb) {
            s[cb] += __shfl_xor(s[cb], 16, 64);
            s[cb] += __shfl_xor(s[cb], 32, 64);
        }
        if (hi == 0) {
            float len = (float)(lb - la);
            float* dst = agg + (size_t)node * 128;
#pragma unroll
            for (int cb = 0; cb < 8; ++cb)
                atomicAdd(dst + cb * 16 + lo, s[cb] + len * be2c[cb]);
        }
    }
}

// ---------------------------------------------------------------------------
// MFMA node update, split-precision A AND B (3-term), both stages:
//   X_out = silu(agg @ W_u1 + b_u1) @ W_u2 + b_u2
// ---------------------------------------------------------------------------
__global__ __launch_bounds__(256, 2)
void nodeupd_kernel(const float* __restrict__ AGG,
                    const unsigned short* __restrict__ pku1h,
                    const unsigned short* __restrict__ pku1l,
                    const float* __restrict__ bu1,
                    const unsigned short* __restrict__ pku2h,
                    const unsigned short* __restrict__ pku2l,
                    const float* __restrict__ bu2,
                    float* __restrict__ Xout)
{
    __shared__ unsigned short s_h[64 * 128];  // 16 KB, swizzled (hi)
    __shared__ unsigned short s_l[64 * 128];  // 16 KB, swizzled (lo)

    const int tid = threadIdx.x;
    const int w = tid >> 6;
    const int lane = tid & 63;
    const int lo = lane & 15, hi = lane >> 4;
    const int r0 = blockIdx.x * 64;
    const int colbase = w * 32;

    for (int i = tid; i < 1024; i += 256) {
        int e = i >> 4, cg = i & 15;
        int r = r0 + e;
        union { unsigned short u16[8]; f4 v; } H, L;
        if (r < NN) {
            f4 v0 = ((const f4*)AGG)[(size_t)r * 32 + cg * 2];
            f4 v1 = ((const f4*)AGG)[(size_t)r * 32 + cg * 2 + 1];
#pragma unroll
            for (int q = 0; q < 4; ++q) {
                unsigned short h0 = f2bf(v0[q]);
                unsigned short h1 = f2bf(v1[q]);
                H.u16[q] = h0;     L.u16[q] = f2bf(v0[q] - bf2f(h0));
                H.u16[4 + q] = h1; L.u16[4 + q] = f2bf(v1[q] - bf2f(h1));
            }
        } else {
#pragma unroll
            for (int q = 0; q < 8; ++q) { H.u16[q] = 0; L.u16[q] = 0; }
        }
        int byte = e * 256 + ((cg * 16) ^ ((e & 7) << 4));
        *reinterpret_cast<f4*>((char*)s_h + byte) = H.v;
        *reinterpret_cast<f4*>((char*)s_l + byte) = L.v;
    }
    __syncthreads();

    // ---- stage 1: t = silu(agg @ Wu1 + b1)
    f32x4 acc[4][2];
#pragma unroll
    for (int rb = 0; rb < 4; ++rb)
#pragma unroll
        for (int cb = 0; cb < 2; ++cb) acc[rb][cb] = (f32x4){0.f, 0.f, 0.f, 0.f};

#pragma unroll
    for (int kc = 0; kc < 4; ++kc) {
        bf16x8 ah[4], al[4];
#pragma unroll
        for (int rb = 0; rb < 4; ++rb) {
            int row = rb * 16 + lo;
            int byte = row * 256 + ((kc * 64 + hi * 16) ^ ((row & 7) << 4));
            ah[rb] = *reinterpret_cast<const bf16x8*>((const char*)s_h + byte);
            al[rb] = *reinterpret_cast<const bf16x8*>((const char*)s_l + byte);
        }
#pragma unroll
        for (int cb = 0; cb < 2; ++cb) {
            size_t boff = ((size_t)((kc * 8 + w * 2 + cb) * 64 + lane)) * 8;
            bf16x8 bh = *reinterpret_cast<const bf16x8*>(pku1h + boff);
            bf16x8 bl = *reinterpret_cast<const bf16x8*>(pku1l + boff);
#pragma unroll
            for (int rb = 0; rb < 4; ++rb) {
                acc[rb][cb] = __builtin_amdgcn_mfma_f32_16x16x32_bf16(ah[rb], bh, acc[rb][cb], 0, 0, 0);
                acc[rb][cb] = __builtin_amdgcn_mfma_f32_16x16x32_bf16(al[rb], bh, acc[rb][cb], 0, 0, 0);
                acc[rb][cb] = __builtin_amdgcn_mfma_f32_16x16x32_bf16(ah[rb], bl, acc[rb][cb], 0, 0, 0);
            }
        }
    }

    float b1c[2];
#pragma unroll
    for (int cb = 0; cb < 2; ++cb) b1c[cb] = bu1[colbase + cb * 16 + lo];

    __syncthreads();  // all stage-1 LDS reads complete before overwrite

#pragma unroll
    for (int rb = 0; rb < 4; ++rb)
#pragma unroll
        for (int r = 0; r < 4; ++r) {
            int row = rb * 16 + hi * 4 + r;
#pragma unroll
            for (int cb = 0; cb < 2; ++cb) {
                int col = colbase + cb * 16 + lo;
                float t = silu1(acc[rb][cb][r] + b1c[cb]);
                unsigned short th = f2bf(t);
                unsigned short tl = f2bf(t - bf2f(th));
                int byte = row * 256 + ((col * 2) ^ ((row & 7) << 4));
                *(unsigned short*)((char*)s_h + byte) = th;
                *(unsigned short*)((char*)s_l + byte) = tl;
            }
        }
    __syncthreads();

    // ---- stage 2: X_out = t @ Wu2 + b2
    f32x4 acc2[4][2];
#pragma unroll
    for (int rb = 0; rb < 4; ++rb)
#pragma unroll
        for (int cb = 0; cb < 2; ++cb) acc2[rb][cb] = (f32x4){0.f, 0.f, 0.f, 0.f};

#pragma unroll
    for (int kc = 0; kc < 4; ++kc) {
        bf16x8 ah[4], al[4];
#pragma unroll
        for (int rb = 0; rb < 4; ++rb) {
            int row = rb * 16 + lo;
            int byte = row * 256 + ((kc * 64 + hi * 16) ^ ((row & 7) << 4));
            ah[rb] = *reinterpret_cast<const bf16x8*>((const char*)s_h + byte);
            al[rb] = *reinterpret_cast<const bf16x8*>((const char*)s_l + byte);
        }
#pragma unroll
        for (int cb = 0; cb < 2; ++cb) {
            size_t boff = ((size_t)((kc * 8 + w * 2 + cb) * 64 + lane)) * 8;
            bf16x8 bh = *reinterpret_cast<const bf16x8*>(pku2h + boff);
            bf16x8 bl = *reinterpret_cast<const bf16x8*>(pku2l + boff);
#pragma unroll
            for (int rb = 0; rb < 4; ++rb) {
                acc2[rb][cb] = __builtin_amdgcn_mfma_f32_16x16x32_bf16(ah[rb], bh, acc2[rb][cb], 0, 0, 0);
                acc2[rb][cb] = __builtin_amdgcn_mfma_f32_16x16x32_bf16(al[rb], bh, acc2[rb][cb], 0, 0, 0);
                acc2[rb][cb] = __builtin_amdgcn_mfma_f32_16x16x32_bf16(ah[rb], bl, acc2[rb][cb], 0, 0, 0);
            }
        }
    }

    float b2c[2];
#pragma unroll
    for (int cb = 0; cb < 2; ++cb) b2c[cb] = bu2[colbase + cb * 16 + lo];

#pragma unroll
    for (int rb = 0; rb < 4; ++rb)
#pragma unroll
        for (int r = 0; r < 4; ++r) {
            int row = r0 + rb * 16 + hi * 4 + r;
            if (row < NN) {
#pragma unroll
                for (int cb = 0; cb < 2; ++cb) {
                    int col = colbase + cb * 16 + lo;
                    Xout[(size_t)row * 128 + col] = acc2[rb][cb][r] + b2c[cb];
                }
            }
        }
}

// ---------------------------------------------------------------------------
// Graph readout: grid (G, 4); block reduces 32 cols of one graph segment
// ---------------------------------------------------------------------------
__global__ void gsum2_kernel(const float* __restrict__ X, const int* __restrict__ gstart,
                             float* __restrict__ Gm)
{
    __shared__ f4 red[32][8];
    int g = blockIdx.x;
    int q = blockIdx.y;
    int cq = threadIdx.x & 7;
    int cf = q * 8 + cq;          // f4 col (0..31)
    int rg = threadIdx.x >> 3;    // 0..31
    int i0 = gstart[g], i1 = gstart[g + 1];
    f4 s = {0.f, 0.f, 0.f, 0.f};
    for (int i = i0 + rg; i < i1; i += 32)
        s += ((const f4*)X)[(size_t)i * 32 + cf];
    red[rg][cq] = s;
    __syncthreads();
    for (int off = 16; off >= 1; off >>= 1) {
        if (rg < off) red[rg][cq] += red[rg + off][cq];
        __syncthreads();
    }
    if (rg == 0) ((f4*)Gm)[g * 32 + cf] = red[0][cq];
}

__global__ void final_kernel(const float* __restrict__ Gm,
                             const float* __restrict__ Wf1, const float* __restrict__ bf1,
                             const float* __restrict__ Wf2, const float* __restrict__ bf2,
                             float* __restrict__ out)
{
    __shared__ float red[128];
    int g = blockIdx.x;
    int j = threadIdx.x;
    float s = bf1[j];
    for (int k = 0; k < 128; ++k) s += Gm[(size_t)g * 128 + k] * Wf1[k * 128 + j];
    s = silu1(s);
    red[j] = s * Wf2[j];
    __syncthreads();
    for (int off = 64; off > 0; off >>= 1) {
        if (j < off) red[j] += red[j + off];
        __syncthreads();
    }
    if (j == 0) out[g] = red[0] + bf2[0];
}

// ---------------------------------------------------------------------------
extern "C" void kernel_launch(void* const* d_in, const int* in_sizes, int n_in,
                              void* d_out, int out_size, void* d_ws, size_t ws_size,
                              hipStream_t stream)
{
    const float* x     = (const float*)d_in[0];
    const float* pos   = (const float*)d_in[1];
    const int*   eidx  = (const int*)d_in[2];
    const int*   batch = (const int*)d_in[3];
    const float* Wnode = (const float*)d_in[4];
    const float* bnode = (const float*)d_in[5];
    const float* Wrbf  = (const float*)d_in[6];
    const float* brbf  = (const float*)d_in[7];
    const float* We1   = (const float*)d_in[8];
    const float* be1   = (const float*)d_in[9];
    const float* We2   = (const float*)d_in[10];
    const float* be2   = (const float*)d_in[11];
    const float* Wu1   = (const float*)d_in[12];
    const float* bu1   = (const float*)d_in[13];
    const float* Wu2   = (const float*)d_in[14];
    const float* bu2   = (const float*)d_in[15];
    const float* Wf1   = (const float*)d_in[16];
    const float* bf1   = (const float*)d_in[17];
    const float* Wf2   = (const float*)d_in[18];
    const float* bf2   = (const float*)d_in[19];

    const int* erow = eidx;
    const int* ecol = eidx + NE;

    char* wsb = (char*)d_ws;
    size_t off = 0;
    auto take = [&](size_t bytes) -> char* {
        char* p = wsb + off;
        off += (bytes + 255) & ~(size_t)255;
        return p;
    };
    float* Pb    = (float*)take((size_t)NN * HH * 4);
    float* Qb    = (float*)take((size_t)NN * HH * 4);
    float* aggb  = (float*)take((size_t)NN * HH * 4);
    float* xa    = (float*)take((size_t)NN * DD * 4);
    float* gm    = (float*)take((size_t)GG * DD * 4);
    float* Wpa   = (float*)take((size_t)LL * DD * HH * 4);
    float* Wqb   = (float*)take((size_t)LL * DD * HH * 4);
    float* Wcc   = (float*)take((size_t)LL * RR * HH * 4);
    float* bmsg  = (float*)take((size_t)LL * HH * 4);
    int*   cnt   = (int*)take((size_t)NN * 4);
    int*   cur   = (int*)take((size_t)NN * 4);
    int*   srow  = (int*)take((size_t)NE * 4);
    int*   scol  = (int*)take((size_t)NE * 4);
    float* sdist = (float*)take((size_t)NE * 4);
    int*   gst   = (int*)take((size_t)(GG + 1) * 4);
    unsigned short* pk1   = (unsigned short*)take((size_t)LL * RR * HH * 2);
    unsigned short* pk3   = (unsigned short*)take((size_t)LL * HH * HH * 2);
    unsigned short* pkpah = (unsigned short*)take((size_t)LL * DD * HH * 2);
    unsigned short* pkpal = (unsigned short*)take((size_t)LL * DD * HH * 2);
    unsigned short* pkqbh = (unsigned short*)take((size_t)LL * DD * HH * 2);
    unsigned short* pkqbl = (unsigned short*)take((size_t)LL * DD * HH * 2);
    unsigned short* pku1h = (unsigned short*)take((size_t)LL * HH * HH * 2);
    unsigned short* pku1l = (unsigned short*)take((size_t)LL * HH * HH * 2);
    unsigned short* pku2h = (unsigned short*)take((size_t)LL * HH * DD * 2);
    unsigned short* pku2l = (unsigned short*)take((size_t)LL * HH * DD * 2);

    if (off > ws_size) return;  // fail loudly (absmax), not a fault

    // ---- one-time preprocessing
    fillz_kernel<<<(NN + 1023) / 1024, 256, 0, stream>>>((float*)cnt, NN / 4);
    hist_kernel<<<(NE + 255) / 256, 256, 0, stream>>>(ecol, cnt);
    scan_kernel<<<1, 1024, 0, stream>>>(cnt, cur);
    scatter_kernel<<<(NE + 255) / 256, 256, 0, stream>>>(pos, erow, ecol, cur, srow, scol, sdist);
    gstart_kernel<<<(NN + 255) / 256, 256, 0, stream>>>(batch, gst);

    dim3 foldgrid((41088 + 255) / 256, LL);
    fold_kernel<<<foldgrid, 256, 0, stream>>>(Wnode, Wrbf, We1, bnode, brbf, be1,
                                              Wpa, Wqb, Wcc, bmsg);
    for (int l = 0; l < LL; ++l) {
        pack_kernel<<<(RR * HH + 255) / 256, 256, 0, stream>>>(
            Wcc + (size_t)l * RR * HH, pk1 + (size_t)l * RR * HH, RR);
        pack_kernel<<<(HH * HH + 255) / 256, 256, 0, stream>>>(
            We2 + (size_t)l * HH * HH, pk3 + (size_t)l * HH * HH, HH);
        pack2_kernel<<<(DD * HH + 255) / 256, 256, 0, stream>>>(
            Wpa + (size_t)l * DD * HH, pkpah + (size_t)l * DD * HH,
            pkpal + (size_t)l * DD * HH, DD);
        pack2_kernel<<<(DD * HH + 255) / 256, 256, 0, stream>>>(
            Wqb + (size_t)l * DD * HH, pkqbh + (size_t)l * DD * HH,
            pkqbl + (size_t)l * DD * HH, DD);
        pack2_kernel<<<(HH * HH + 255) / 256, 256, 0, stream>>>(
            Wu1 + (size_t)l * HH * HH, pku1h + (size_t)l * HH * HH,
            pku1l + (size_t)l * HH * HH, HH);
        pack2_kernel<<<(HH * DD + 255) / 256, 256, 0, stream>>>(
            Wu2 + (size_t)l * HH * DD, pku2h + (size_t)l * HH * DD,
            pku2l + (size_t)l * HH * DD, HH);
    }

    // ---- layers
    const int nblk = (NN + 63) / 64;
    const float* xin = x;
    for (int l = 0; l < LL; ++l) {
        nodepq_kernel<<<nblk, 256, 0, stream>>>(xin,
                                                pkpah + (size_t)l * DD * HH,
                                                pkpal + (size_t)l * DD * HH,
                                                pkqbh + (size_t)l * DD * HH,
                                                pkqbl + (size_t)l * DD * HH,
                                                Pb, Qb, aggb);
        edge_mfma_kernel<<<NE / EB, 256, 0, stream>>>(Pb, Qb, sdist, srow, scol,
                                                      pk1 + (size_t)l * RR * HH,
                                                      pk3 + (size_t)l * HH * HH,
                                                      bmsg + (size_t)l * HH,
                                                      be2 + (size_t)l * HH, aggb);
        nodeupd_kernel<<<nblk, 256, 0, stream>>>(aggb,
                                                 pku1h + (size_t)l * HH * HH,
                                                 pku1l + (size_t)l * HH * HH,
                                                 bu1 + (size_t)l * HH,
                                                 pku2h + (size_t)l * HH * DD,
                                                 pku2l + (size_t)l * HH * DD,
                                                 bu2 + (size_t)l * DD, xa);
        xin = xa;
    }

    dim3 gsgrid(GG, 4);
    gsum2_kernel<<<gsgrid, 256, 0, stream>>>(xin, gst, gm);
    final_kernel<<<GG, 128, 0, stream>>>(gm, Wf1, bf1, Wf2, bf2, (float*)d_out);
}